// Round 2
// baseline (2081.277 us; speedup 1.0000x reference)
//
#include <hip/hip_runtime.h>
#include <math.h>

#define NB 2
#define TT 2048
#define CC 2048
#define HH 16
#define DD 128

// d_out layout (floats): out [N,T,C] | k [N,H,T,D] | v [N,H,T,D]
#define ELEMS_OUT ((size_t)NB * TT * CC)          // 8388608
#define ELEMS_KV  ((size_t)NB * HH * TT * DD)     // 8388608

typedef __attribute__((ext_vector_type(8))) short bf16x8;
typedef __attribute__((ext_vector_type(4))) float f32x4;

// Split fp32 into bf16 hi (truncate) + bf16 lo (truncate of remainder).
// v = hi + lo + err, |err| <= 2^-16 |v|.  r = v - hi is exact in fp32.
__device__ __forceinline__ void split_bf16(float v, unsigned short& hi, unsigned short& lo) {
    const unsigned u = __float_as_uint(v);
    hi = (unsigned short)(u >> 16);
    const float r = v - __uint_as_float(u & 0xffff0000u);
    lo = (unsigned short)(__float_as_uint(r) >> 16);
}

// ---------------------------------------------------------------------------
// conv_hl: row-major fp32 -> hi/lo bf16 planes (same layout), float4-wide.
// ---------------------------------------------------------------------------
__global__ __launch_bounds__(256)
void conv_hl(const float* __restrict__ src, unsigned short* __restrict__ hi,
             unsigned short* __restrict__ lo, int n4)
{
    for (int i = blockIdx.x * 256 + threadIdx.x; i < n4; i += gridDim.x * 256) {
        const float4 v = ((const float4*)src)[i];
        unsigned short h0, h1, h2, h3, l0, l1, l2, l3;
        split_bf16(v.x, h0, l0);
        split_bf16(v.y, h1, l1);
        split_bf16(v.z, h2, l2);
        split_bf16(v.w, h3, l3);
        ((ushort4*)hi)[i] = make_ushort4(h0, h1, h2, h3);
        ((ushort4*)lo)[i] = make_ushort4(l0, l1, l2, l3);
    }
}

// ---------------------------------------------------------------------------
// tconv: wo [2048][2048] fp32 -> transposed hi/lo bf16 [2048][2048] (dst[c][r]).
// 32x32 tiles via padded LDS.
// ---------------------------------------------------------------------------
__global__ __launch_bounds__(256)
void tconv_kernel(const float* __restrict__ src, unsigned short* __restrict__ dhi,
                  unsigned short* __restrict__ dlo)
{
    __shared__ float T[32][33];
    const int tx = threadIdx.x & 31;
    const int ty = threadIdx.x >> 5;           // 0..7
    const int c0 = blockIdx.x * 32;
    const int r0 = blockIdx.y * 32;
#pragma unroll
    for (int i = 0; i < 4; ++i)
        T[ty + 8 * i][tx] = src[(size_t)(r0 + ty + 8 * i) * 2048 + c0 + tx];
    __syncthreads();
#pragma unroll
    for (int i = 0; i < 4; ++i) {
        const float v = T[tx][ty + 8 * i];     // = src[r0+tx][c0+ty+8i]
        unsigned short h, l;
        split_bf16(v, h, l);
        const size_t o = (size_t)(c0 + ty + 8 * i) * 2048 + r0 + tx;
        dhi[o] = h;
        dlo[o] = l;
    }
}

// ---------------------------------------------------------------------------
// bf16x3 MFMA GEMM core (128x128 tile, BK=32, 4 waves 2x2, 64x64 per wave).
// LDS layout [hl][slot][129 rows (+1 pad)][8 k]:
//   - slot pad makes slot-stride = 516 dwords (== 4 mod 32 banks) so both the
//     b128 staging writes (16 rows x 4 slots / wave) and the b128 fragment
//     reads (4 slots x 16 rows / wave) hit the conflict-free 8-cycle minimum.
// Fragment: lane l -> row base + (l&15), k-group g = l>>4 (slot g), 8 contig k.
// A and B staged with the SAME (lane,reg)->k convention, so the dot product is
// correct for any consistent hardware k-bijection.
// ---------------------------------------------------------------------------
#define MFMA_GEMM_BODY(AHI, ALO, BHI, BLO, M0, J0)                                   \
    const int tid  = threadIdx.x;                                                    \
    const int lane = tid & 63;                                                       \
    const int w    = tid >> 6;                                                       \
    const int wr   = w >> 1, wc = w & 1;                                             \
    const int lr   = lane & 15, g = lane >> 4;                                       \
    __shared__ __align__(16) unsigned short As[2][4][129][8];                        \
    __shared__ __align__(16) unsigned short Bs[2][4][129][8];                        \
    f32x4 acc[4][4];                                                                 \
    _Pragma("unroll")                                                                \
    for (int m = 0; m < 4; ++m)                                                      \
        _Pragma("unroll")                                                            \
        for (int n = 0; n < 4; ++n) acc[m][n] = (f32x4){0.f, 0.f, 0.f, 0.f};         \
    for (int kt = 0; kt < CC; kt += 32) {                                            \
        __syncthreads();                                                             \
        _Pragma("unroll")                                                            \
        for (int it = 0; it < 4; ++it) {                                             \
            const int hl   = it >> 1;                                                \
            const int rem  = tid + (it & 1) * 256;                                   \
            const int row  = rem >> 2;                                               \
            const int slot = rem & 3;                                                \
            const unsigned short* ap = (hl ? ALO : AHI)                              \
                + (size_t)(M0 + row) * 2048 + kt + slot * 8;                         \
            *(bf16x8*)&As[hl][slot][row][0] = *(const bf16x8*)ap;                    \
            const unsigned short* bp = (hl ? BLO : BHI)                              \
                + (size_t)(J0 + row) * 2048 + kt + slot * 8;                         \
            *(bf16x8*)&Bs[hl][slot][row][0] = *(const bf16x8*)bp;                    \
        }                                                                            \
        __syncthreads();                                                             \
        bf16x8 ah[4], al[4];                                                         \
        _Pragma("unroll")                                                            \
        for (int m = 0; m < 4; ++m) {                                                \
            ah[m] = *(const bf16x8*)&As[0][g][wr * 64 + m * 16 + lr][0];             \
            al[m] = *(const bf16x8*)&As[1][g][wr * 64 + m * 16 + lr][0];             \
        }                                                                            \
        _Pragma("unroll")                                                            \
        for (int n = 0; n < 4; ++n) {                                                \
            const bf16x8 bh = *(const bf16x8*)&Bs[0][g][wc * 64 + n * 16 + lr][0];   \
            const bf16x8 bl = *(const bf16x8*)&Bs[1][g][wc * 64 + n * 16 + lr][0];   \
            _Pragma("unroll")                                                        \
            for (int m = 0; m < 4; ++m) {                                            \
                f32x4 t = acc[m][n];                                                 \
                t = __builtin_amdgcn_mfma_f32_16x16x32_bf16(al[m], bh, t, 0, 0, 0);  \
                t = __builtin_amdgcn_mfma_f32_16x16x32_bf16(ah[m], bl, t, 0, 0, 0);  \
                t = __builtin_amdgcn_mfma_f32_16x16x32_bf16(ah[m], bh, t, 0, 0, 0);  \
                acc[m][n] = t;                                                       \
            }                                                                        \
        }                                                                            \
    }

// QKV projection: A = x_hl [4096][2048], B = wqkv_hl [6144][2048] (rows=out cols)
__global__ __launch_bounds__(256, 3)
void mfma_qkv_kernel(const unsigned short* __restrict__ ahi,
                     const unsigned short* __restrict__ alo,
                     const unsigned short* __restrict__ bhi,
                     const unsigned short* __restrict__ blo,
                     float* __restrict__ qb, float* __restrict__ kb,
                     float* __restrict__ vb)
{
    const int j0 = blockIdx.x * 128;
    const int m0 = blockIdx.y * 128;
    MFMA_GEMM_BODY(ahi, alo, bhi, blo, m0, j0)

    // C/D layout (m89): col = lane&15, row = (lane>>4)*4 + reg
    const int p = j0 >> 11;
    const int h = (j0 & 2047) >> 7;
    float* outb = (p == 0) ? qb : ((p == 1) ? kb : vb);
#pragma unroll
    for (int m = 0; m < 4; ++m) {
#pragma unroll
        for (int r = 0; r < 4; ++r) {
            const int gm = m0 + wr * 64 + m * 16 + g * 4 + r;
            const int nb = gm >> 11;
            const int t  = gm & 2047;
            float* rowp = outb + ((size_t)(nb * HH + h) * TT + t) * DD;
#pragma unroll
            for (int n = 0; n < 4; ++n)
                rowp[wc * 64 + n * 16 + lr] = acc[m][n][r];
        }
    }
}

// Out projection: A = y_hl [4096][2048], B = wot_hl [2048][2048] (pre-transposed)
__global__ __launch_bounds__(256, 3)
void mfma_oproj_kernel(const unsigned short* __restrict__ ahi,
                       const unsigned short* __restrict__ alo,
                       const unsigned short* __restrict__ bhi,
                       const unsigned short* __restrict__ blo,
                       float* __restrict__ outp)
{
    const int j0 = blockIdx.x * 128;
    const int m0 = blockIdx.y * 128;
    MFMA_GEMM_BODY(ahi, alo, bhi, blo, m0, j0)

#pragma unroll
    for (int m = 0; m < 4; ++m) {
#pragma unroll
        for (int r = 0; r < 4; ++r) {
            const int gm = m0 + wr * 64 + m * 16 + g * 4 + r;
            float* rowp = outp + (size_t)gm * 2048 + j0;
#pragma unroll
            for (int n = 0; n < 4; ++n)
                rowp[wc * 64 + n * 16 + lr] = acc[m][n][r];
        }
    }
}

// ---------------------------------------------------------------------------
// Causal flash attention per (n,h), 64-row Q tile per block (fp32 VALU).
// Writes y either as fp32 [4096][2048] or as hi/lo bf16 planes (fast path).
// ---------------------------------------------------------------------------
__global__ __launch_bounds__(256, 1)
void attn_kernel(const float* __restrict__ qg,
                 const float* __restrict__ kg,
                 const float* __restrict__ vg,
                 float* __restrict__ yf32,
                 unsigned short* __restrict__ yhi,
                 unsigned short* __restrict__ ylo,
                 int write_bf16)
{
    const int tid = threadIdx.x;
    const int tx  = tid & 15;
    const int ty  = tid >> 4;
    const int qt  = blockIdx.x;         // 0..31
    const int nh  = blockIdx.y;         // 0..31
    const int n   = nh >> 4;
    const int h   = nh & 15;

    const float* Q = qg + (size_t)nh * TT * DD;
    const float* K = kg + (size_t)nh * TT * DD;
    const float* V = vg + (size_t)nh * TT * DD;

    __shared__ float Qs[64][128];       // swizzled
    __shared__ float Ks[64][128];       // swizzled
    __shared__ float Vs[64][128];       // linear
    __shared__ float Ps[64][68];        // +4 pad

    const int qr0 = qt * 64;

#pragma unroll
    for (int it = 0; it < 8; ++it) {
        const int f4 = tid + it * 256;
        const int r  = f4 >> 5;
        const int c4 = f4 & 31;
        const float4 qv = *(const float4*)(Q + (size_t)(qr0 + r) * DD + c4 * 4);
        *(float4*)&Qs[r][(c4 ^ (r & 7)) << 2] = qv;
    }

    float acc[4][8];
#pragma unroll
    for (int i = 0; i < 4; ++i)
#pragma unroll
        for (int c = 0; c < 8; ++c) acc[i][c] = 0.f;

    float mrow[4], lrow[4];
#pragma unroll
    for (int i = 0; i < 4; ++i) { mrow[i] = -INFINITY; lrow[i] = 0.f; }

    const float sm_scale = 0.08838834764831845f;   // 1/sqrt(128)

    for (int jt = 0; jt <= qt; ++jt) {
        const int s0 = jt * 64;

        __syncthreads();
#pragma unroll
        for (int it = 0; it < 8; ++it) {
            const int f4 = tid + it * 256;
            const int r  = f4 >> 5;
            const int c4 = f4 & 31;
            const float4 kv = *(const float4*)(K + (size_t)(s0 + r) * DD + c4 * 4);
            *(float4*)&Ks[r][(c4 ^ (r & 7)) << 2] = kv;
            const float4 vv = *(const float4*)(V + (size_t)(s0 + r) * DD + c4 * 4);
            *(float4*)&Vs[r][c4 << 2] = vv;
        }
        __syncthreads();

        float S[4][4];
#pragma unroll
        for (int i = 0; i < 4; ++i)
#pragma unroll
            for (int j = 0; j < 4; ++j) S[i][j] = 0.f;

#pragma unroll 8
        for (int k4 = 0; k4 < 32; ++k4) {
            const int bsl = (k4 ^ (tx & 7)) << 2;   // (tx+16w)&7 == tx&7
            const float4 b0 = *(const float4*)&Ks[tx     ][bsl];
            const float4 b1 = *(const float4*)&Ks[tx + 16][bsl];
            const float4 b2 = *(const float4*)&Ks[tx + 32][bsl];
            const float4 b3 = *(const float4*)&Ks[tx + 48][bsl];
#pragma unroll
            for (int i = 0; i < 4; ++i) {
                const int r = ty * 4 + i;
                const float4 a = *(const float4*)&Qs[r][(k4 ^ (r & 7)) << 2];
                S[i][0] = fmaf(a.w, b0.w, fmaf(a.z, b0.z, fmaf(a.y, b0.y, fmaf(a.x, b0.x, S[i][0]))));
                S[i][1] = fmaf(a.w, b1.w, fmaf(a.z, b1.z, fmaf(a.y, b1.y, fmaf(a.x, b1.x, S[i][1]))));
                S[i][2] = fmaf(a.w, b2.w, fmaf(a.z, b2.z, fmaf(a.y, b2.y, fmaf(a.x, b2.x, S[i][2]))));
                S[i][3] = fmaf(a.w, b3.w, fmaf(a.z, b3.z, fmaf(a.y, b3.y, fmaf(a.x, b3.x, S[i][3]))));
            }
        }

        const bool diag = (jt == qt);
#pragma unroll
        for (int i = 0; i < 4; ++i)
#pragma unroll
            for (int j = 0; j < 4; ++j) {
                float s = S[i][j] * sm_scale;
                if (diag && (tx + 16 * j > ty * 4 + i)) s = -INFINITY;
                S[i][j] = s;
            }

#pragma unroll
        for (int i = 0; i < 4; ++i) {
            float tm = fmaxf(fmaxf(S[i][0], S[i][1]), fmaxf(S[i][2], S[i][3]));
            tm = fmaxf(tm, __shfl_xor(tm, 1, 16));
            tm = fmaxf(tm, __shfl_xor(tm, 2, 16));
            tm = fmaxf(tm, __shfl_xor(tm, 4, 16));
            tm = fmaxf(tm, __shfl_xor(tm, 8, 16));
            const float mnew = fmaxf(mrow[i], tm);
            const float corr = expf(mrow[i] - mnew);
            mrow[i] = mnew;
            float rs = 0.f;
#pragma unroll
            for (int j = 0; j < 4; ++j) {
                const float pv = expf(S[i][j] - mnew);
                S[i][j] = pv;
                rs += pv;
            }
            rs += __shfl_xor(rs, 1, 16);
            rs += __shfl_xor(rs, 2, 16);
            rs += __shfl_xor(rs, 4, 16);
            rs += __shfl_xor(rs, 8, 16);
            lrow[i] = lrow[i] * corr + rs;
#pragma unroll
            for (int c = 0; c < 8; ++c) acc[i][c] *= corr;
            const int r = ty * 4 + i;
#pragma unroll
            for (int j = 0; j < 4; ++j) Ps[r][tx + 16 * j] = S[i][j];
        }
        __syncthreads();

#pragma unroll 4
        for (int s4 = 0; s4 < 16; ++s4) {
            const float4 p0 = *(const float4*)&Ps[ty * 4 + 0][s4 * 4];
            const float4 p1 = *(const float4*)&Ps[ty * 4 + 1][s4 * 4];
            const float4 p2 = *(const float4*)&Ps[ty * 4 + 2][s4 * 4];
            const float4 p3 = *(const float4*)&Ps[ty * 4 + 3][s4 * 4];
            const float pa[4][4] = {{p0.x, p0.y, p0.z, p0.w},
                                    {p1.x, p1.y, p1.z, p1.w},
                                    {p2.x, p2.y, p2.z, p2.w},
                                    {p3.x, p3.y, p3.z, p3.w}};
#pragma unroll
            for (int ww = 0; ww < 4; ++ww) {
                const int s = s4 * 4 + ww;
                const float4 va = *(const float4*)&Vs[s][tx * 4];
                const float4 vb = *(const float4*)&Vs[s][64 + tx * 4];
#pragma unroll
                for (int i = 0; i < 4; ++i) {
                    const float pv = pa[i][ww];
                    acc[i][0] = fmaf(pv, va.x, acc[i][0]);
                    acc[i][1] = fmaf(pv, va.y, acc[i][1]);
                    acc[i][2] = fmaf(pv, va.z, acc[i][2]);
                    acc[i][3] = fmaf(pv, va.w, acc[i][3]);
                    acc[i][4] = fmaf(pv, vb.x, acc[i][4]);
                    acc[i][5] = fmaf(pv, vb.y, acc[i][5]);
                    acc[i][6] = fmaf(pv, vb.z, acc[i][6]);
                    acc[i][7] = fmaf(pv, vb.w, acc[i][7]);
                }
            }
        }
    }

    // epilogue: y[m = n*2048+qr][h*128 + d], d in {tx*4..tx*4+3, 64+tx*4..}
    if (write_bf16) {
#pragma unroll
        for (int i = 0; i < 4; ++i) {
            const float inv = 1.f / lrow[i];
            const int qr = qr0 + ty * 4 + i;
            const size_t base = (size_t)(n * 2048 + qr) * 2048 + h * 128;
            unsigned short hh[8], ll[8];
#pragma unroll
            for (int c = 0; c < 8; ++c) split_bf16(acc[i][c] * inv, hh[c], ll[c]);
            *(ushort4*)(yhi + base + tx * 4)      = make_ushort4(hh[0], hh[1], hh[2], hh[3]);
            *(ushort4*)(yhi + base + 64 + tx * 4) = make_ushort4(hh[4], hh[5], hh[6], hh[7]);
            *(ushort4*)(ylo + base + tx * 4)      = make_ushort4(ll[0], ll[1], ll[2], ll[3]);
            *(ushort4*)(ylo + base + 64 + tx * 4) = make_ushort4(ll[4], ll[5], ll[6], ll[7]);
        }
    } else {
#pragma unroll
        for (int i = 0; i < 4; ++i) {
            const float inv = 1.f / lrow[i];
            const int qr = qr0 + ty * 4 + i;
            float* rowp = yf32 + (size_t)(n * 2048 + qr) * 2048 + h * 128;
            const float4 o0 = make_float4(acc[i][0] * inv, acc[i][1] * inv, acc[i][2] * inv, acc[i][3] * inv);
            const float4 o1 = make_float4(acc[i][4] * inv, acc[i][5] * inv, acc[i][6] * inv, acc[i][7] * inv);
            *(float4*)(rowp + tx * 4)      = o0;
            *(float4*)(rowp + 64 + tx * 4) = o1;
        }
    }
}

// ---------------------------------------------------------------------------
// Fallback fp32 GEMMs (used only if ws is too small for the hi/lo planes).
// ---------------------------------------------------------------------------
__global__ __launch_bounds__(256, 2)
void qkv_proj_kernel(const float* __restrict__ x,
                     const float* __restrict__ wq,
                     const float* __restrict__ wk,
                     const float* __restrict__ wv,
                     float* __restrict__ q_buf,
                     float* __restrict__ k_out,
                     float* __restrict__ v_out)
{
    const int tid = threadIdx.x;
    const int tx  = tid & 15;
    const int ty  = tid >> 4;
    const int j0  = blockIdx.x * 128;
    const int m0  = blockIdx.y * 128;

    const int    p   = j0 >> 11;
    const int    jw0 = j0 & 2047;
    const float* W    = (p == 0) ? wq    : ((p == 1) ? wk    : wv);
    float*       outb = (p == 0) ? q_buf : ((p == 1) ? k_out : v_out);

    __shared__ float At[16][132];
    __shared__ float Bt[16][132];

    float acc[8][8];
#pragma unroll
    for (int i = 0; i < 8; ++i)
#pragma unroll
        for (int j = 0; j < 8; ++j) acc[i][j] = 0.f;

    for (int kt = 0; kt < CC; kt += 16) {
        __syncthreads();
#pragma unroll
        for (int it = 0; it < 2; ++it) {
            const int f4  = tid + it * 256;
            const int row = f4 >> 2;
            const int kf4 = f4 & 3;
            const float4 a = *(const float4*)(x + (size_t)(m0 + row) * CC + kt + kf4 * 4);
            At[kf4 * 4 + 0][row] = a.x;
            At[kf4 * 4 + 1][row] = a.y;
            At[kf4 * 4 + 2][row] = a.z;
            At[kf4 * 4 + 3][row] = a.w;
            const float4 b = *(const float4*)(W + (size_t)(jw0 + row) * CC + kt + kf4 * 4);
            Bt[kf4 * 4 + 0][row] = b.x;
            Bt[kf4 * 4 + 1][row] = b.y;
            Bt[kf4 * 4 + 2][row] = b.z;
            Bt[kf4 * 4 + 3][row] = b.w;
        }
        __syncthreads();

#pragma unroll
        for (int k = 0; k < 16; ++k) {
            const float4 a0 = *(const float4*)&At[k][ty * 4];
            const float4 a1 = *(const float4*)&At[k][64 + ty * 4];
            const float4 b0 = *(const float4*)&Bt[k][tx * 4];
            const float4 b1 = *(const float4*)&Bt[k][64 + tx * 4];
            const float av[8] = {a0.x, a0.y, a0.z, a0.w, a1.x, a1.y, a1.z, a1.w};
            const float bv[8] = {b0.x, b0.y, b0.z, b0.w, b1.x, b1.y, b1.z, b1.w};
#pragma unroll
            for (int i = 0; i < 8; ++i)
#pragma unroll
                for (int j = 0; j < 8; ++j)
                    acc[i][j] = fmaf(av[i], bv[j], acc[i][j]);
        }
    }

    const int h = jw0 >> 7;
#pragma unroll
    for (int rh = 0; rh < 2; ++rh) {
#pragma unroll
        for (int i = 0; i < 4; ++i) {
            const int m = m0 + rh * 64 + ty * 4 + i;
            const int n = m >> 11;
            const int t = m & 2047;
            float* rowp = outb + ((size_t)(n * HH + h) * TT + t) * DD;
            const int ai = rh * 4 + i;
            const float4 o0 = make_float4(acc[ai][0], acc[ai][1], acc[ai][2], acc[ai][3]);
            const float4 o1 = make_float4(acc[ai][4], acc[ai][5], acc[ai][6], acc[ai][7]);
            *(float4*)(rowp + tx * 4)      = o0;
            *(float4*)(rowp + 64 + tx * 4) = o1;
        }
    }
}

__global__ __launch_bounds__(256, 2)
void out_proj_kernel(const float* __restrict__ y,
                     const float* __restrict__ wo,
                     float* __restrict__ out)
{
    const int tid = threadIdx.x;
    const int tx  = tid & 15;
    const int ty  = tid >> 4;
    const int c0  = blockIdx.x * 128;
    const int m0  = blockIdx.y * 128;

    __shared__ float At[16][132];
    __shared__ float Bs[16][132];

    float acc[8][8];
#pragma unroll
    for (int i = 0; i < 8; ++i)
#pragma unroll
        for (int j = 0; j < 8; ++j) acc[i][j] = 0.f;

    for (int kt = 0; kt < 2048; kt += 16) {
        __syncthreads();
#pragma unroll
        for (int it = 0; it < 2; ++it) {
            const int f4 = tid + it * 256;
            {
                const int row = f4 >> 2;
                const int kf4 = f4 & 3;
                const float4 a = *(const float4*)(y + (size_t)(m0 + row) * 2048 + kt + kf4 * 4);
                At[kf4 * 4 + 0][row] = a.x;
                At[kf4 * 4 + 1][row] = a.y;
                At[kf4 * 4 + 2][row] = a.z;
                At[kf4 * 4 + 3][row] = a.w;
            }
            {
                const int row = f4 >> 5;
                const int cf4 = f4 & 31;
                const float4 b = *(const float4*)(wo + (size_t)(kt + row) * 2048 + c0 + cf4 * 4);
                *(float4*)&Bs[row][cf4 * 4] = b;
            }
        }
        __syncthreads();

#pragma unroll
        for (int k = 0; k < 16; ++k) {
            const float4 a0 = *(const float4*)&At[k][ty * 4];
            const float4 a1 = *(const float4*)&At[k][64 + ty * 4];
            const float4 b0 = *(const float4*)&Bs[k][tx * 4];
            const float4 b1 = *(const float4*)&Bs[k][64 + tx * 4];
            const float av[8] = {a0.x, a0.y, a0.z, a0.w, a1.x, a1.y, a1.z, a1.w};
            const float bv[8] = {b0.x, b0.y, b0.z, b0.w, b1.x, b1.y, b1.z, b1.w};
#pragma unroll
            for (int i = 0; i < 8; ++i)
#pragma unroll
                for (int j = 0; j < 8; ++j)
                    acc[i][j] = fmaf(av[i], bv[j], acc[i][j]);
        }
    }

#pragma unroll
    for (int rh = 0; rh < 2; ++rh) {
#pragma unroll
        for (int i = 0; i < 4; ++i) {
            const int m  = m0 + rh * 64 + ty * 4 + i;
            const int ai = rh * 4 + i;
#pragma unroll
            for (int ch = 0; ch < 2; ++ch) {
                const float4 o = make_float4(acc[ai][ch * 4 + 0], acc[ai][ch * 4 + 1],
                                             acc[ai][ch * 4 + 2], acc[ai][ch * 4 + 3]);
                *(float4*)(out + (size_t)m * 2048 + c0 + ch * 64 + tx * 4) = o;
            }
        }
    }
}

// ---------------------------------------------------------------------------
extern "C" void kernel_launch(void* const* d_in, const int* in_sizes, int n_in,
                              void* d_out, int out_size, void* d_ws, size_t ws_size,
                              hipStream_t stream)
{
    const float* x  = (const float*)d_in[0];
    const float* wq = (const float*)d_in[1];
    const float* wk = (const float*)d_in[2];
    const float* wv = (const float*)d_in[3];
    const float* wo = (const float*)d_in[4];

    float* out   = (float*)d_out;
    float* k_out = out + ELEMS_OUT;
    float* v_out = k_out + ELEMS_KV;
    float* q_buf = out;                 // out slot unused until out-proj

    const size_t NEED = 134217728;      // 128 MiB of hi/lo planes
    if (ws_size >= NEED) {
        // ws layout (ushorts):
        //   x_hl  [2][4096][2048], wqkv_hl [2][6144][2048] (q|k|v rows),
        //   wot_hl[2][2048][2048] (wo^T),  y_hl [2][4096][2048]
        unsigned short* xhi   = (unsigned short*)d_ws;
        unsigned short* xlo   = xhi + 8388608;
        unsigned short* whi   = xlo + 8388608;
        unsigned short* wlo   = whi + 12582912;
        unsigned short* wothi = wlo + 12582912;
        unsigned short* wotlo = wothi + 4194304;
        unsigned short* yhi   = wotlo + 4194304;
        unsigned short* ylo   = yhi + 8388608;

        conv_hl<<<dim3(2048), dim3(256), 0, stream>>>(x, xhi, xlo, 2097152);
        conv_hl<<<dim3(1024), dim3(256), 0, stream>>>(wq, whi,           wlo,           1048576);
        conv_hl<<<dim3(1024), dim3(256), 0, stream>>>(wk, whi + 4194304, wlo + 4194304, 1048576);
        conv_hl<<<dim3(1024), dim3(256), 0, stream>>>(wv, whi + 8388608, wlo + 8388608, 1048576);
        tconv_kernel<<<dim3(64, 64), dim3(256), 0, stream>>>(wo, wothi, wotlo);

        mfma_qkv_kernel<<<dim3(48, 32), dim3(256), 0, stream>>>(xhi, xlo, whi, wlo,
                                                                q_buf, k_out, v_out);
        attn_kernel<<<dim3(32, 32), dim3(256), 0, stream>>>(q_buf, k_out, v_out,
                                                            nullptr, yhi, ylo, 1);
        mfma_oproj_kernel<<<dim3(16, 32), dim3(256), 0, stream>>>(yhi, ylo, wothi, wotlo, out);
    } else {
        float* y_buf = (float*)d_ws;    // fp32 y, 33.6 MB
        qkv_proj_kernel<<<dim3(48, 32), dim3(256), 0, stream>>>(x, wq, wk, wv,
                                                                q_buf, k_out, v_out);
        attn_kernel<<<dim3(32, 32), dim3(256), 0, stream>>>(q_buf, k_out, v_out,
                                                            y_buf, nullptr, nullptr, 0);
        out_proj_kernel<<<dim3(16, 32), dim3(256), 0, stream>>>(y_buf, wo, out);
    }
}

// Round 3
// 760.583 us; speedup vs baseline: 2.7364x; 2.7364x over previous
//
#include <hip/hip_runtime.h>
#include <math.h>

#define NB 2
#define TT 2048
#define CC 2048
#define HH 16
#define DD 128

// d_out layout (floats): out [N,T,C] | k [N,H,T,D] | v [N,H,T,D]
#define ELEMS_OUT ((size_t)NB * TT * CC)          // 8388608
#define ELEMS_KV  ((size_t)NB * HH * TT * DD)     // 8388608

typedef __attribute__((ext_vector_type(8))) short bf16x8;
typedef __attribute__((ext_vector_type(4))) float f32x4;

// Split fp32 into bf16 hi (truncate) + bf16 lo (truncate of remainder).
// v = hi + lo + err, |err| <= 2^-16 |v|.  r = v - hi is exact in fp32.
__device__ __forceinline__ void split_bf16(float v, unsigned short& hi, unsigned short& lo) {
    const unsigned u = __float_as_uint(v);
    hi = (unsigned short)(u >> 16);
    const float r = v - __uint_as_float(u & 0xffff0000u);
    lo = (unsigned short)(__float_as_uint(r) >> 16);
}

__device__ __forceinline__ unsigned short bf16_rtn(float v) {
    unsigned u = __float_as_uint(v);
    u += 0x7fff + ((u >> 16) & 1);
    return (unsigned short)(u >> 16);
}

// ---------------------------------------------------------------------------
// conv_hl: row-major fp32 -> hi/lo bf16 planes (same layout), float4-wide.
// ---------------------------------------------------------------------------
__global__ __launch_bounds__(256)
void conv_hl(const float* __restrict__ src, unsigned short* __restrict__ hi,
             unsigned short* __restrict__ lo, int n4)
{
    for (int i = blockIdx.x * 256 + threadIdx.x; i < n4; i += gridDim.x * 256) {
        const float4 v = ((const float4*)src)[i];
        unsigned short h0, h1, h2, h3, l0, l1, l2, l3;
        split_bf16(v.x, h0, l0);
        split_bf16(v.y, h1, l1);
        split_bf16(v.z, h2, l2);
        split_bf16(v.w, h3, l3);
        ((ushort4*)hi)[i] = make_ushort4(h0, h1, h2, h3);
        ((ushort4*)lo)[i] = make_ushort4(l0, l1, l2, l3);
    }
}

// ---------------------------------------------------------------------------
// tconv: wo [2048][2048] fp32 -> transposed hi/lo bf16 [2048][2048] (dst[c][r]).
// ---------------------------------------------------------------------------
__global__ __launch_bounds__(256)
void tconv_kernel(const float* __restrict__ src, unsigned short* __restrict__ dhi,
                  unsigned short* __restrict__ dlo)
{
    __shared__ float T[32][33];
    const int tx = threadIdx.x & 31;
    const int ty = threadIdx.x >> 5;           // 0..7
    const int c0 = blockIdx.x * 32;
    const int r0 = blockIdx.y * 32;
#pragma unroll
    for (int i = 0; i < 4; ++i)
        T[ty + 8 * i][tx] = src[(size_t)(r0 + ty + 8 * i) * 2048 + c0 + tx];
    __syncthreads();
#pragma unroll
    for (int i = 0; i < 4; ++i) {
        const float v = T[tx][ty + 8 * i];     // = src[r0+tx][c0+ty+8i]
        unsigned short h, l;
        split_bf16(v, h, l);
        const size_t o = (size_t)(c0 + ty + 8 * i) * 2048 + r0 + tx;
        dhi[o] = h;
        dlo[o] = l;
    }
}

// ---------------------------------------------------------------------------
// bf16x3 MFMA GEMM core (128x128 tile, BK=32, 4 waves 2x2, 64x64 per wave).
// (validated round 2: passed, absmax 0.03125)
// ---------------------------------------------------------------------------
#define MFMA_GEMM_BODY(AHI, ALO, BHI, BLO, M0, J0)                                   \
    const int tid  = threadIdx.x;                                                    \
    const int lane = tid & 63;                                                       \
    const int w    = tid >> 6;                                                       \
    const int wr   = w >> 1, wc = w & 1;                                             \
    const int lr   = lane & 15, g = lane >> 4;                                       \
    __shared__ __align__(16) unsigned short As[2][4][129][8];                        \
    __shared__ __align__(16) unsigned short Bs[2][4][129][8];                        \
    f32x4 acc[4][4];                                                                 \
    _Pragma("unroll")                                                                \
    for (int m = 0; m < 4; ++m)                                                      \
        _Pragma("unroll")                                                            \
        for (int n = 0; n < 4; ++n) acc[m][n] = (f32x4){0.f, 0.f, 0.f, 0.f};         \
    for (int kt = 0; kt < CC; kt += 32) {                                            \
        __syncthreads();                                                             \
        _Pragma("unroll")                                                            \
        for (int it = 0; it < 4; ++it) {                                             \
            const int hl   = it >> 1;                                                \
            const int rem  = tid + (it & 1) * 256;                                   \
            const int row  = rem >> 2;                                               \
            const int slot = rem & 3;                                                \
            const unsigned short* ap = (hl ? ALO : AHI)                              \
                + (size_t)(M0 + row) * 2048 + kt + slot * 8;                         \
            *(bf16x8*)&As[hl][slot][row][0] = *(const bf16x8*)ap;                    \
            const unsigned short* bp = (hl ? BLO : BHI)                              \
                + (size_t)(J0 + row) * 2048 + kt + slot * 8;                         \
            *(bf16x8*)&Bs[hl][slot][row][0] = *(const bf16x8*)bp;                    \
        }                                                                            \
        __syncthreads();                                                             \
        bf16x8 ah[4], al[4];                                                         \
        _Pragma("unroll")                                                            \
        for (int m = 0; m < 4; ++m) {                                                \
            ah[m] = *(const bf16x8*)&As[0][g][wr * 64 + m * 16 + lr][0];             \
            al[m] = *(const bf16x8*)&As[1][g][wr * 64 + m * 16 + lr][0];             \
        }                                                                            \
        _Pragma("unroll")                                                            \
        for (int n = 0; n < 4; ++n) {                                                \
            const bf16x8 bh = *(const bf16x8*)&Bs[0][g][wc * 64 + n * 16 + lr][0];   \
            const bf16x8 bl = *(const bf16x8*)&Bs[1][g][wc * 64 + n * 16 + lr][0];   \
            _Pragma("unroll")                                                        \
            for (int m = 0; m < 4; ++m) {                                            \
                f32x4 t = acc[m][n];                                                 \
                t = __builtin_amdgcn_mfma_f32_16x16x32_bf16(al[m], bh, t, 0, 0, 0);  \
                t = __builtin_amdgcn_mfma_f32_16x16x32_bf16(ah[m], bl, t, 0, 0, 0);  \
                t = __builtin_amdgcn_mfma_f32_16x16x32_bf16(ah[m], bh, t, 0, 0, 0);  \
                acc[m][n] = t;                                                       \
            }                                                                        \
        }                                                                            \
    }

__global__ __launch_bounds__(256, 3)
void mfma_qkv_kernel(const unsigned short* __restrict__ ahi,
                     const unsigned short* __restrict__ alo,
                     const unsigned short* __restrict__ bhi,
                     const unsigned short* __restrict__ blo,
                     float* __restrict__ qb, float* __restrict__ kb,
                     float* __restrict__ vb)
{
    const int j0 = blockIdx.x * 128;
    const int m0 = blockIdx.y * 128;
    MFMA_GEMM_BODY(ahi, alo, bhi, blo, m0, j0)

    // C/D layout (m89): col = lane&15, row = (lane>>4)*4 + reg
    const int p = j0 >> 11;
    const int h = (j0 & 2047) >> 7;
    float* outb = (p == 0) ? qb : ((p == 1) ? kb : vb);
#pragma unroll
    for (int m = 0; m < 4; ++m) {
#pragma unroll
        for (int r = 0; r < 4; ++r) {
            const int gm = m0 + wr * 64 + m * 16 + g * 4 + r;
            const int nb = gm >> 11;
            const int t  = gm & 2047;
            float* rowp = outb + ((size_t)(nb * HH + h) * TT + t) * DD;
#pragma unroll
            for (int n = 0; n < 4; ++n)
                rowp[wc * 64 + n * 16 + lr] = acc[m][n][r];
        }
    }
}

__global__ __launch_bounds__(256, 3)
void mfma_oproj_kernel(const unsigned short* __restrict__ ahi,
                       const unsigned short* __restrict__ alo,
                       const unsigned short* __restrict__ bhi,
                       const unsigned short* __restrict__ blo,
                       float* __restrict__ outp)
{
    const int j0 = blockIdx.x * 128;
    const int m0 = blockIdx.y * 128;
    MFMA_GEMM_BODY(ahi, alo, bhi, blo, m0, j0)

#pragma unroll
    for (int m = 0; m < 4; ++m) {
#pragma unroll
        for (int r = 0; r < 4; ++r) {
            const int gm = m0 + wr * 64 + m * 16 + g * 4 + r;
            float* rowp = outp + (size_t)gm * 2048 + j0;
#pragma unroll
            for (int n = 0; n < 4; ++n)
                rowp[wc * 64 + n * 16 + lr] = acc[m][n][r];
        }
    }
}

// ---------------------------------------------------------------------------
// MFMA causal flash attention.
//   Block: (qt descending, nh). 512 threads / 8 waves; wave w owns 16 q-rows.
//   QBLK=128 q-rows/block, KV tiles of 64.
//   QK^T: bf16x3 (Q,K split hi/lo) -> scores exact to ~2^-15.
//   PV:   P bf16 (RTN), V bf16 (RTN), fp32 accum.
//   Fragment convention == validated GEMM: A/B row = base+(l&15), k-slot
//   g=l>>4, 8 contig k.  C: col=l&15, row=4*(l>>4)+reg.
// ---------------------------------------------------------------------------
#define QBLK 128
#define KVB 64

__global__ __launch_bounds__(512, 1)
void attn_mfma_kernel(const float* __restrict__ qg,
                      const float* __restrict__ kg,
                      const float* __restrict__ vg,
                      unsigned short* __restrict__ yhi,
                      unsigned short* __restrict__ ylo)
{
    const int tid  = threadIdx.x;
    const int lane = tid & 63;
    const int w    = tid >> 6;          // wave 0..7
    const int lr   = lane & 15;
    const int g    = lane >> 4;         // 0..3
    const int bx   = blockIdx.x;        // 0..511
    const int qt   = 15 - (bx >> 5);    // descending work size for LPT packing
    const int nh   = bx & 31;
    const int n    = nh >> 4;
    const int h    = nh & 15;
    const int qr0  = qt * QBLK;

    const float* Q = qg + (size_t)nh * TT * DD;
    const float* K = kg + (size_t)nh * TT * DD;
    const float* V = vg + (size_t)nh * TT * DD;

    // LDS: K hi/lo [hl][kc][g][s pad 66][8k] 33.8KB; V^T hi [d][s pad 72] 18.4KB;
    // P per-wave [16 qrow][s pad 72] 18.4KB.  Total 70.7 KB.
    __shared__ __align__(16) unsigned short Ks[2][4][4][66][8];
    __shared__ __align__(16) unsigned short Vt[128][72];
    __shared__ __align__(16) unsigned short Ps[8][16][72];

    // ---- Q fragments (hi/lo) for this wave's 16 rows, once per block ----
    bf16x8 qh[4], ql[4];
    {
        const int qr = qr0 + w * 16 + lr;
#pragma unroll
        for (int kc = 0; kc < 4; ++kc) {
            const float* p = Q + (size_t)qr * DD + kc * 32 + g * 8;
            const float4 f0 = *(const float4*)p;
            const float4 f1 = *(const float4*)(p + 4);
            const float f[8] = {f0.x, f0.y, f0.z, f0.w, f1.x, f1.y, f1.z, f1.w};
            bf16x8 hv, lv;
#pragma unroll
            for (int j = 0; j < 8; ++j) {
                unsigned short hu, lu;
                split_bf16(f[j], hu, lu);
                hv[j] = (short)hu;
                lv[j] = (short)lu;
            }
            qh[kc] = hv;
            ql[kc] = lv;
        }
    }

    f32x4 o[8];
#pragma unroll
    for (int n2 = 0; n2 < 8; ++n2) o[n2] = (f32x4){0.f, 0.f, 0.f, 0.f};
    float m2[4], lsum[4];
#pragma unroll
    for (int r = 0; r < 4; ++r) { m2[r] = -INFINITY; lsum[r] = 0.f; }

    const float c2 = 0.08838834764831845f * 1.44269504088896f;  // /sqrt(128)*log2e

    const int jmax = 2 * qt + 1;
    for (int jt = 0; jt <= jmax; ++jt) {
        const int s0 = jt * KVB;

        __syncthreads();
        // ---- stage K hi/lo (split on the fly) ----
#pragma unroll
        for (int it = 0; it < 2; ++it) {
            const int u  = tid + it * 512;      // 0..1023 = 64 s x 16 k8
            const int s  = u >> 4;
            const int k8 = u & 15;
            const int kc = k8 >> 2, gg = k8 & 3;
            const float* p = K + (size_t)(s0 + s) * DD + k8 * 8;
            const float4 f0 = *(const float4*)p;
            const float4 f1 = *(const float4*)(p + 4);
            const float f[8] = {f0.x, f0.y, f0.z, f0.w, f1.x, f1.y, f1.z, f1.w};
            bf16x8 hv, lv;
#pragma unroll
            for (int j = 0; j < 8; ++j) {
                unsigned short hu, lu;
                split_bf16(f[j], hu, lu);
                hv[j] = (short)hu;
                lv[j] = (short)lu;
            }
            *(bf16x8*)&Ks[0][kc][gg][s][0] = hv;
            *(bf16x8*)&Ks[1][kc][gg][s][0] = lv;
        }
        // ---- stage V transposed (hi only, RTN) ----
#pragma unroll
        for (int it = 0; it < 4; ++it) {
            const int u  = tid + it * 512;      // 0..2047 = 64 s x 32 d4
            const int d4 = u & 31;
            const int s  = u >> 5;
            const float4 f = *(const float4*)(V + (size_t)(s0 + s) * DD + d4 * 4);
            Vt[d4 * 4 + 0][s] = bf16_rtn(f.x);
            Vt[d4 * 4 + 1][s] = bf16_rtn(f.y);
            Vt[d4 * 4 + 2][s] = bf16_rtn(f.z);
            Vt[d4 * 4 + 3][s] = bf16_rtn(f.w);
        }
        __syncthreads();

        // ---- S = Q K^T (bf16x3) ----
        f32x4 sa[4];
#pragma unroll
        for (int nn = 0; nn < 4; ++nn) {
            f32x4 t = (f32x4){0.f, 0.f, 0.f, 0.f};
#pragma unroll
            for (int kc = 0; kc < 4; ++kc) {
                const bf16x8 kh = *(const bf16x8*)&Ks[0][kc][g][nn * 16 + lr][0];
                const bf16x8 kl = *(const bf16x8*)&Ks[1][kc][g][nn * 16 + lr][0];
                t = __builtin_amdgcn_mfma_f32_16x16x32_bf16(ql[kc], kh, t, 0, 0, 0);
                t = __builtin_amdgcn_mfma_f32_16x16x32_bf16(qh[kc], kl, t, 0, 0, 0);
                t = __builtin_amdgcn_mfma_f32_16x16x32_bf16(qh[kc], kh, t, 0, 0, 0);
            }
            sa[nn] = t;
        }

        // ---- online softmax (exp2 domain), C rows = qr0+w*16+4g+r ----
        const int qbase = qr0 + w * 16 + g * 4;
        const bool domask = (s0 + 63 > qr0 + w * 16);
#pragma unroll
        for (int r = 0; r < 4; ++r) {
            float sv[4];
#pragma unroll
            for (int nn = 0; nn < 4; ++nn) {
                float s = sa[nn][r] * c2;
                if (domask && (s0 + nn * 16 + lr > qbase + r)) s = -INFINITY;
                sv[nn] = s;
            }
            float mr = fmaxf(fmaxf(sv[0], sv[1]), fmaxf(sv[2], sv[3]));
            mr = fmaxf(mr, __shfl_xor(mr, 1));
            mr = fmaxf(mr, __shfl_xor(mr, 2));
            mr = fmaxf(mr, __shfl_xor(mr, 4));
            mr = fmaxf(mr, __shfl_xor(mr, 8));
            const float mnew = fmaxf(m2[r], mr);
            const float corr = exp2f(m2[r] - mnew);     // 0 on first tile
            m2[r] = mnew;
            float rs = 0.f;
#pragma unroll
            for (int nn = 0; nn < 4; ++nn) {
                const float pv = exp2f(sv[nn] - mnew);
                rs += pv;
                Ps[w][g * 4 + r][nn * 16 + lr] = bf16_rtn(pv);
            }
            rs += __shfl_xor(rs, 1);
            rs += __shfl_xor(rs, 2);
            rs += __shfl_xor(rs, 4);
            rs += __shfl_xor(rs, 8);
            lsum[r] = lsum[r] * corr + rs;
#pragma unroll
            for (int n2 = 0; n2 < 8; ++n2) o[n2][r] *= corr;
        }

        // ---- O += P V (own-wave P region; within-wave lgkmcnt ordering) ----
#pragma unroll
        for (int kc2 = 0; kc2 < 2; ++kc2) {
            const bf16x8 pa = *(const bf16x8*)&Ps[w][lr][kc2 * 32 + g * 8];
#pragma unroll
            for (int n2 = 0; n2 < 8; ++n2) {
                const bf16x8 vb = *(const bf16x8*)&Vt[n2 * 16 + lr][kc2 * 32 + g * 8];
                o[n2] = __builtin_amdgcn_mfma_f32_16x16x32_bf16(pa, vb, o[n2], 0, 0, 0);
            }
        }
    }

    // ---- epilogue: y[m][h*128+d] as hi/lo bf16 planes ----
#pragma unroll
    for (int r = 0; r < 4; ++r) {
        const float inv = 1.f / lsum[r];
        const int gm = n * 2048 + qr0 + w * 16 + g * 4 + r;
        const size_t base = (size_t)gm * 2048 + h * 128;
#pragma unroll
        for (int n2 = 0; n2 < 8; ++n2) {
            unsigned short hu, lu;
            split_bf16(o[n2][r] * inv, hu, lu);
            yhi[base + n2 * 16 + lr] = hu;
            ylo[base + n2 * 16 + lr] = lu;
        }
    }
}

// ---------------------------------------------------------------------------
// Fallback fp32 attention (only if ws too small for hi/lo planes).
// ---------------------------------------------------------------------------
__global__ __launch_bounds__(256, 1)
void attn_kernel(const float* __restrict__ qg,
                 const float* __restrict__ kg,
                 const float* __restrict__ vg,
                 float* __restrict__ yf32)
{
    const int tid = threadIdx.x;
    const int tx  = tid & 15;
    const int ty  = tid >> 4;
    const int qt  = blockIdx.x;
    const int nh  = blockIdx.y;
    const int n   = nh >> 4;
    const int h   = nh & 15;

    const float* Q = qg + (size_t)nh * TT * DD;
    const float* K = kg + (size_t)nh * TT * DD;
    const float* V = vg + (size_t)nh * TT * DD;

    __shared__ float Qs[64][128];
    __shared__ float Ks2[64][128];
    __shared__ float Vs[64][128];
    __shared__ float Ps2[64][68];

    const int qr0 = qt * 64;

#pragma unroll
    for (int it = 0; it < 8; ++it) {
        const int f4 = tid + it * 256;
        const int r  = f4 >> 5;
        const int c4 = f4 & 31;
        const float4 qv = *(const float4*)(Q + (size_t)(qr0 + r) * DD + c4 * 4);
        *(float4*)&Qs[r][(c4 ^ (r & 7)) << 2] = qv;
    }

    float acc[4][8];
#pragma unroll
    for (int i = 0; i < 4; ++i)
#pragma unroll
        for (int c = 0; c < 8; ++c) acc[i][c] = 0.f;

    float mrow[4], lrow[4];
#pragma unroll
    for (int i = 0; i < 4; ++i) { mrow[i] = -INFINITY; lrow[i] = 0.f; }

    const float sm_scale = 0.08838834764831845f;

    for (int jt = 0; jt <= qt; ++jt) {
        const int s0 = jt * 64;
        __syncthreads();
#pragma unroll
        for (int it = 0; it < 8; ++it) {
            const int f4 = tid + it * 256;
            const int r  = f4 >> 5;
            const int c4 = f4 & 31;
            const float4 kv = *(const float4*)(K + (size_t)(s0 + r) * DD + c4 * 4);
            *(float4*)&Ks2[r][(c4 ^ (r & 7)) << 2] = kv;
            const float4 vv = *(const float4*)(V + (size_t)(s0 + r) * DD + c4 * 4);
            *(float4*)&Vs[r][c4 << 2] = vv;
        }
        __syncthreads();

        float S[4][4];
#pragma unroll
        for (int i = 0; i < 4; ++i)
#pragma unroll
            for (int j = 0; j < 4; ++j) S[i][j] = 0.f;

#pragma unroll 8
        for (int k4 = 0; k4 < 32; ++k4) {
            const int bsl = (k4 ^ (tx & 7)) << 2;
            const float4 b0 = *(const float4*)&Ks2[tx     ][bsl];
            const float4 b1 = *(const float4*)&Ks2[tx + 16][bsl];
            const float4 b2 = *(const float4*)&Ks2[tx + 32][bsl];
            const float4 b3 = *(const float4*)&Ks2[tx + 48][bsl];
#pragma unroll
            for (int i = 0; i < 4; ++i) {
                const int r = ty * 4 + i;
                const float4 a = *(const float4*)&Qs[r][(k4 ^ (r & 7)) << 2];
                S[i][0] = fmaf(a.w, b0.w, fmaf(a.z, b0.z, fmaf(a.y, b0.y, fmaf(a.x, b0.x, S[i][0]))));
                S[i][1] = fmaf(a.w, b1.w, fmaf(a.z, b1.z, fmaf(a.y, b1.y, fmaf(a.x, b1.x, S[i][1]))));
                S[i][2] = fmaf(a.w, b2.w, fmaf(a.z, b2.z, fmaf(a.y, b2.y, fmaf(a.x, b2.x, S[i][2]))));
                S[i][3] = fmaf(a.w, b3.w, fmaf(a.z, b3.z, fmaf(a.y, b3.y, fmaf(a.x, b3.x, S[i][3]))));
            }
        }

        const bool diag = (jt == qt);
#pragma unroll
        for (int i = 0; i < 4; ++i)
#pragma unroll
            for (int j = 0; j < 4; ++j) {
                float s = S[i][j] * sm_scale;
                if (diag && (tx + 16 * j > ty * 4 + i)) s = -INFINITY;
                S[i][j] = s;
            }

#pragma unroll
        for (int i = 0; i < 4; ++i) {
            float tm = fmaxf(fmaxf(S[i][0], S[i][1]), fmaxf(S[i][2], S[i][3]));
            tm = fmaxf(tm, __shfl_xor(tm, 1, 16));
            tm = fmaxf(tm, __shfl_xor(tm, 2, 16));
            tm = fmaxf(tm, __shfl_xor(tm, 4, 16));
            tm = fmaxf(tm, __shfl_xor(tm, 8, 16));
            const float mnew = fmaxf(mrow[i], tm);
            const float corr = expf(mrow[i] - mnew);
            mrow[i] = mnew;
            float rs = 0.f;
#pragma unroll
            for (int j = 0; j < 4; ++j) {
                const float pv = expf(S[i][j] - mnew);
                S[i][j] = pv;
                rs += pv;
            }
            rs += __shfl_xor(rs, 1, 16);
            rs += __shfl_xor(rs, 2, 16);
            rs += __shfl_xor(rs, 4, 16);
            rs += __shfl_xor(rs, 8, 16);
            lrow[i] = lrow[i] * corr + rs;
#pragma unroll
            for (int c = 0; c < 8; ++c) acc[i][c] *= corr;
            const int r = ty * 4 + i;
#pragma unroll
            for (int j = 0; j < 4; ++j) Ps2[r][tx + 16 * j] = S[i][j];
        }
        __syncthreads();

#pragma unroll 4
        for (int s4 = 0; s4 < 16; ++s4) {
            const float4 p0 = *(const float4*)&Ps2[ty * 4 + 0][s4 * 4];
            const float4 p1 = *(const float4*)&Ps2[ty * 4 + 1][s4 * 4];
            const float4 p2 = *(const float4*)&Ps2[ty * 4 + 2][s4 * 4];
            const float4 p3 = *(const float4*)&Ps2[ty * 4 + 3][s4 * 4];
            const float pa[4][4] = {{p0.x, p0.y, p0.z, p0.w},
                                    {p1.x, p1.y, p1.z, p1.w},
                                    {p2.x, p2.y, p2.z, p2.w},
                                    {p3.x, p3.y, p3.z, p3.w}};
#pragma unroll
            for (int ww = 0; ww < 4; ++ww) {
                const int s = s4 * 4 + ww;
                const float4 va = *(const float4*)&Vs[s][tx * 4];
                const float4 vb = *(const float4*)&Vs[s][64 + tx * 4];
#pragma unroll
                for (int i = 0; i < 4; ++i) {
                    const float pv = pa[i][ww];
                    acc[i][0] = fmaf(pv, va.x, acc[i][0]);
                    acc[i][1] = fmaf(pv, va.y, acc[i][1]);
                    acc[i][2] = fmaf(pv, va.z, acc[i][2]);
                    acc[i][3] = fmaf(pv, va.w, acc[i][3]);
                    acc[i][4] = fmaf(pv, vb.x, acc[i][4]);
                    acc[i][5] = fmaf(pv, vb.y, acc[i][5]);
                    acc[i][6] = fmaf(pv, vb.z, acc[i][6]);
                    acc[i][7] = fmaf(pv, vb.w, acc[i][7]);
                }
            }
        }
    }

#pragma unroll
    for (int i = 0; i < 4; ++i) {
        const float inv = 1.f / lrow[i];
        const int qr = qr0 + ty * 4 + i;
        float* rowp = yf32 + (size_t)(n * 2048 + qr) * 2048 + h * 128;
        const float4 o0 = make_float4(acc[i][0] * inv, acc[i][1] * inv, acc[i][2] * inv, acc[i][3] * inv);
        const float4 o1 = make_float4(acc[i][4] * inv, acc[i][5] * inv, acc[i][6] * inv, acc[i][7] * inv);
        *(float4*)(rowp + tx * 4)      = o0;
        *(float4*)(rowp + 64 + tx * 4) = o1;
    }
}

// ---------------------------------------------------------------------------
// Fallback fp32 GEMMs (ws too small).
// ---------------------------------------------------------------------------
__global__ __launch_bounds__(256, 2)
void qkv_proj_kernel(const float* __restrict__ x,
                     const float* __restrict__ wq,
                     const float* __restrict__ wk,
                     const float* __restrict__ wv,
                     float* __restrict__ q_buf,
                     float* __restrict__ k_out,
                     float* __restrict__ v_out)
{
    const int tid = threadIdx.x;
    const int tx  = tid & 15;
    const int ty  = tid >> 4;
    const int j0  = blockIdx.x * 128;
    const int m0  = blockIdx.y * 128;

    const int    p   = j0 >> 11;
    const int    jw0 = j0 & 2047;
    const float* W    = (p == 0) ? wq    : ((p == 1) ? wk    : wv);
    float*       outb = (p == 0) ? q_buf : ((p == 1) ? k_out : v_out);

    __shared__ float At[16][132];
    __shared__ float Bt[16][132];

    float acc[8][8];
#pragma unroll
    for (int i = 0; i < 8; ++i)
#pragma unroll
        for (int j = 0; j < 8; ++j) acc[i][j] = 0.f;

    for (int kt = 0; kt < CC; kt += 16) {
        __syncthreads();
#pragma unroll
        for (int it = 0; it < 2; ++it) {
            const int f4  = tid + it * 256;
            const int row = f4 >> 2;
            const int kf4 = f4 & 3;
            const float4 a = *(const float4*)(x + (size_t)(m0 + row) * CC + kt + kf4 * 4);
            At[kf4 * 4 + 0][row] = a.x;
            At[kf4 * 4 + 1][row] = a.y;
            At[kf4 * 4 + 2][row] = a.z;
            At[kf4 * 4 + 3][row] = a.w;
            const float4 b = *(const float4*)(W + (size_t)(jw0 + row) * CC + kt + kf4 * 4);
            Bt[kf4 * 4 + 0][row] = b.x;
            Bt[kf4 * 4 + 1][row] = b.y;
            Bt[kf4 * 4 + 2][row] = b.z;
            Bt[kf4 * 4 + 3][row] = b.w;
        }
        __syncthreads();

#pragma unroll
        for (int k = 0; k < 16; ++k) {
            const float4 a0 = *(const float4*)&At[k][ty * 4];
            const float4 a1 = *(const float4*)&At[k][64 + ty * 4];
            const float4 b0 = *(const float4*)&Bt[k][tx * 4];
            const float4 b1 = *(const float4*)&Bt[k][64 + tx * 4];
            const float av[8] = {a0.x, a0.y, a0.z, a0.w, a1.x, a1.y, a1.z, a1.w};
            const float bv[8] = {b0.x, b0.y, b0.z, b0.w, b1.x, b1.y, b1.z, b1.w};
#pragma unroll
            for (int i = 0; i < 8; ++i)
#pragma unroll
                for (int j = 0; j < 8; ++j)
                    acc[i][j] = fmaf(av[i], bv[j], acc[i][j]);
        }
    }

    const int h = jw0 >> 7;
#pragma unroll
    for (int rh = 0; rh < 2; ++rh) {
#pragma unroll
        for (int i = 0; i < 4; ++i) {
            const int m = m0 + rh * 64 + ty * 4 + i;
            const int n = m >> 11;
            const int t = m & 2047;
            float* rowp = outb + ((size_t)(n * HH + h) * TT + t) * DD;
            const int ai = rh * 4 + i;
            const float4 o0 = make_float4(acc[ai][0], acc[ai][1], acc[ai][2], acc[ai][3]);
            const float4 o1 = make_float4(acc[ai][4], acc[ai][5], acc[ai][6], acc[ai][7]);
            *(float4*)(rowp + tx * 4)      = o0;
            *(float4*)(rowp + 64 + tx * 4) = o1;
        }
    }
}

__global__ __launch_bounds__(256, 2)
void out_proj_kernel(const float* __restrict__ y,
                     const float* __restrict__ wo,
                     float* __restrict__ out)
{
    const int tid = threadIdx.x;
    const int tx  = tid & 15;
    const int ty  = tid >> 4;
    const int c0  = blockIdx.x * 128;
    const int m0  = blockIdx.y * 128;

    __shared__ float At[16][132];
    __shared__ float Bs2[16][132];

    float acc[8][8];
#pragma unroll
    for (int i = 0; i < 8; ++i)
#pragma unroll
        for (int j = 0; j < 8; ++j) acc[i][j] = 0.f;

    for (int kt = 0; kt < 2048; kt += 16) {
        __syncthreads();
#pragma unroll
        for (int it = 0; it < 2; ++it) {
            const int f4 = tid + it * 256;
            {
                const int row = f4 >> 2;
                const int kf4 = f4 & 3;
                const float4 a = *(const float4*)(y + (size_t)(m0 + row) * 2048 + kt + kf4 * 4);
                At[kf4 * 4 + 0][row] = a.x;
                At[kf4 * 4 + 1][row] = a.y;
                At[kf4 * 4 + 2][row] = a.z;
                At[kf4 * 4 + 3][row] = a.w;
            }
            {
                const int row = f4 >> 5;
                const int cf4 = f4 & 31;
                const float4 b = *(const float4*)(wo + (size_t)(kt + row) * 2048 + c0 + cf4 * 4);
                *(float4*)&Bs2[row][cf4 * 4] = b;
            }
        }
        __syncthreads();

#pragma unroll
        for (int k = 0; k < 16; ++k) {
            const float4 a0 = *(const float4*)&At[k][ty * 4];
            const float4 a1 = *(const float4*)&At[k][64 + ty * 4];
            const float4 b0 = *(const float4*)&Bs2[k][tx * 4];
            const float4 b1 = *(const float4*)&Bs2[k][64 + tx * 4];
            const float av[8] = {a0.x, a0.y, a0.z, a0.w, a1.x, a1.y, a1.z, a1.w};
            const float bv[8] = {b0.x, b0.y, b0.z, b0.w, b1.x, b1.y, b1.z, b1.w};
#pragma unroll
            for (int i = 0; i < 8; ++i)
#pragma unroll
                for (int j = 0; j < 8; ++j)
                    acc[i][j] = fmaf(av[i], bv[j], acc[i][j]);
        }
    }

#pragma unroll
    for (int rh = 0; rh < 2; ++rh) {
#pragma unroll
        for (int i = 0; i < 4; ++i) {
            const int m  = m0 + rh * 64 + ty * 4 + i;
            const int ai = rh * 4 + i;
#pragma unroll
            for (int ch = 0; ch < 2; ++ch) {
                const float4 o = make_float4(acc[ai][ch * 4 + 0], acc[ai][ch * 4 + 1],
                                             acc[ai][ch * 4 + 2], acc[ai][ch * 4 + 3]);
                *(float4*)(out + (size_t)m * 2048 + c0 + ch * 64 + tx * 4) = o;
            }
        }
    }
}

// ---------------------------------------------------------------------------
extern "C" void kernel_launch(void* const* d_in, const int* in_sizes, int n_in,
                              void* d_out, int out_size, void* d_ws, size_t ws_size,
                              hipStream_t stream)
{
    const float* x  = (const float*)d_in[0];
    const float* wq = (const float*)d_in[1];
    const float* wk = (const float*)d_in[2];
    const float* wv = (const float*)d_in[3];
    const float* wo = (const float*)d_in[4];

    float* out   = (float*)d_out;
    float* k_out = out + ELEMS_OUT;
    float* v_out = k_out + ELEMS_KV;
    float* q_buf = out;                 // out slot unused until out-proj

    const size_t NEED = 134217728;      // 128 MiB of hi/lo planes
    if (ws_size >= NEED) {
        unsigned short* xhi   = (unsigned short*)d_ws;
        unsigned short* xlo   = xhi + 8388608;
        unsigned short* whi   = xlo + 8388608;
        unsigned short* wlo   = whi + 12582912;
        unsigned short* wothi = wlo + 12582912;
        unsigned short* wotlo = wothi + 4194304;
        unsigned short* yhi   = wotlo + 4194304;
        unsigned short* ylo   = yhi + 8388608;

        conv_hl<<<dim3(2048), dim3(256), 0, stream>>>(x, xhi, xlo, 2097152);
        conv_hl<<<dim3(1024), dim3(256), 0, stream>>>(wq, whi,           wlo,           1048576);
        conv_hl<<<dim3(1024), dim3(256), 0, stream>>>(wk, whi + 4194304, wlo + 4194304, 1048576);
        conv_hl<<<dim3(1024), dim3(256), 0, stream>>>(wv, whi + 8388608, wlo + 8388608, 1048576);
        tconv_kernel<<<dim3(64, 64), dim3(256), 0, stream>>>(wo, wothi, wotlo);

        mfma_qkv_kernel<<<dim3(48, 32), dim3(256), 0, stream>>>(xhi, xlo, whi, wlo,
                                                                q_buf, k_out, v_out);
        attn_mfma_kernel<<<dim3(512), dim3(512), 0, stream>>>(q_buf, k_out, v_out, yhi, ylo);
        mfma_oproj_kernel<<<dim3(16, 32), dim3(256), 0, stream>>>(yhi, ylo, wothi, wotlo, out);
    } else {
        float* y_buf = (float*)d_ws;    // fp32 y, 33.6 MB
        qkv_proj_kernel<<<dim3(48, 32), dim3(256), 0, stream>>>(x, wq, wk, wv,
                                                                q_buf, k_out, v_out);
        attn_kernel<<<dim3(32, 32), dim3(256), 0, stream>>>(q_buf, k_out, v_out, y_buf);
        out_proj_kernel<<<dim3(16, 32), dim3(256), 0, stream>>>(y_buf, wo, out);
    }
}

// Round 8
// 750.711 us; speedup vs baseline: 2.7724x; 1.0132x over previous
//
#include <hip/hip_runtime.h>
#include <math.h>

#define NB 2
#define TT 2048
#define CC 2048
#define HH 16
#define DD 128

// d_out layout (floats): out [N,T,C] | k [N,H,T,D] | v [N,H,T,D]
#define ELEMS_OUT ((size_t)NB * TT * CC)          // 8388608
#define ELEMS_KV  ((size_t)NB * HH * TT * DD)     // 8388608

typedef __attribute__((ext_vector_type(8))) short bf16x8;
typedef __attribute__((ext_vector_type(4))) float f32x4;

// Split fp32 into bf16 hi (truncate) + bf16 lo (truncate of remainder).
__device__ __forceinline__ void split_bf16(float v, unsigned short& hi, unsigned short& lo) {
    const unsigned u = __float_as_uint(v);
    hi = (unsigned short)(u >> 16);
    const float r = v - __uint_as_float(u & 0xffff0000u);
    lo = (unsigned short)(__float_as_uint(r) >> 16);
}

__device__ __forceinline__ unsigned short bf16_rtn(float v) {
    unsigned u = __float_as_uint(v);
    u += 0x7fff + ((u >> 16) & 1);
    return (unsigned short)(u >> 16);
}

// async global->LDS, 16B per lane; dest must be waveBase + lane*16 (linear).
__device__ __forceinline__ void gload16(const void* gsrc, void* ldst) {
    __builtin_amdgcn_global_load_lds(
        (const __attribute__((address_space(1))) void*)gsrc,
        (__attribute__((address_space(3))) void*)ldst, 16, 0, 0);
}

// ---------------------------------------------------------------------------
// conv_hl: row-major fp32 -> hi/lo bf16 planes (same layout), float4-wide.
// ---------------------------------------------------------------------------
__global__ __launch_bounds__(256)
void conv_hl(const float* __restrict__ src, unsigned short* __restrict__ hi,
             unsigned short* __restrict__ lo, int n4)
{
    for (int i = blockIdx.x * 256 + threadIdx.x; i < n4; i += gridDim.x * 256) {
        const float4 v = ((const float4*)src)[i];
        unsigned short h0, h1, h2, h3, l0, l1, l2, l3;
        split_bf16(v.x, h0, l0);
        split_bf16(v.y, h1, l1);
        split_bf16(v.z, h2, l2);
        split_bf16(v.w, h3, l3);
        ((ushort4*)hi)[i] = make_ushort4(h0, h1, h2, h3);
        ((ushort4*)lo)[i] = make_ushort4(l0, l1, l2, l3);
    }
}

// ---------------------------------------------------------------------------
// tconv: wo [2048][2048] fp32 -> transposed hi/lo bf16 (dst[c][r]).
// ---------------------------------------------------------------------------
__global__ __launch_bounds__(256)
void tconv_kernel(const float* __restrict__ src, unsigned short* __restrict__ dhi,
                  unsigned short* __restrict__ dlo)
{
    __shared__ float T[32][33];
    const int tx = threadIdx.x & 31;
    const int ty = threadIdx.x >> 5;           // 0..7
    const int c0 = blockIdx.x * 32;
    const int r0 = blockIdx.y * 32;
#pragma unroll
    for (int i = 0; i < 4; ++i)
        T[ty + 8 * i][tx] = src[(size_t)(r0 + ty + 8 * i) * 2048 + c0 + tx];
    __syncthreads();
#pragma unroll
    for (int i = 0; i < 4; ++i) {
        const float v = T[tx][ty + 8 * i];     // = src[r0+tx][c0+ty+8i]
        unsigned short h, l;
        split_bf16(v, h, l);
        const size_t o = (size_t)(c0 + ty + 8 * i) * 2048 + r0 + tx;
        dhi[o] = h;
        dlo[o] = l;
    }
}

// ---------------------------------------------------------------------------
// vtrans: v [nh][2048 s][128 d] fp32 -> vt [nh][128 d][2048 s] bf16 (RTN).
// 64s x 128d tile per block via LDS.
// ---------------------------------------------------------------------------
__global__ __launch_bounds__(256)
void vtrans_kernel(const float* __restrict__ v, unsigned short* __restrict__ vt)
{
    __shared__ __align__(16) unsigned short Td[128][72];
    const int t  = threadIdx.x;
    const int s0 = blockIdx.x * 64;
    const int nh = blockIdx.y;
    const float* src = v + (size_t)nh * TT * DD;
#pragma unroll
    for (int j = 0; j < 8; ++j) {
        const int u  = t + j * 256;            // 0..2047
        const int s  = u >> 5;
        const int d4 = u & 31;
        const float4 f = *(const float4*)(src + (size_t)(s0 + s) * DD + d4 * 4);
        Td[d4 * 4 + 0][s] = bf16_rtn(f.x);
        Td[d4 * 4 + 1][s] = bf16_rtn(f.y);
        Td[d4 * 4 + 2][s] = bf16_rtn(f.z);
        Td[d4 * 4 + 3][s] = bf16_rtn(f.w);
    }
    __syncthreads();
#pragma unroll
    for (int j = 0; j < 4; ++j) {
        const int u = t + j * 256;             // 0..1023
        const int d = u >> 3;
        const int c = u & 7;
        const bf16x8 val = *(const bf16x8*)&Td[d][c * 8];
        *(bf16x8*)(vt + ((size_t)nh * DD + d) * TT + s0 + c * 8) = val;
    }
}

// ---------------------------------------------------------------------------
// bf16x3 MFMA QKV GEMM: 256x128 tile, BK=32, 4 waves (2x2), wave-tile 128x64.
// LDS linear [hl][rows][32] for global_load_lds; source pre-swizzled with
// slot^(row&3), reads apply the same XOR -> all ds_read_b128 at bank floor.
// ---------------------------------------------------------------------------
__global__ __launch_bounds__(256, 2)
void mfma_qkv_kernel(const unsigned short* __restrict__ ahi,
                     const unsigned short* __restrict__ alo,
                     const unsigned short* __restrict__ bhi,
                     const unsigned short* __restrict__ blo,
                     float* __restrict__ qb, float* __restrict__ kb,
                     float* __restrict__ vb)
{
    const int tid  = threadIdx.x;
    const int lane = tid & 63;
    const int w    = tid >> 6;
    const int wr   = w >> 1, wc = w & 1;
    const int lr   = lane & 15, g = lane >> 4;
    const int j0   = blockIdx.x * 128;
    const int m0   = blockIdx.y * 256;

    __shared__ __align__(16) unsigned short As[2][256][32];
    __shared__ __align__(16) unsigned short Bs[2][128][32];

    f32x4 acc[8][4];
#pragma unroll
    for (int mi = 0; mi < 8; ++mi)
#pragma unroll
        for (int ni = 0; ni < 4; ++ni) acc[mi][ni] = (f32x4){0.f, 0.f, 0.f, 0.f};

    const int crow = lane >> 2;       // within-chunk row 0..15
    const int asl  = lane & 3;        // 16B slot within 64B row

    for (int kt = 0; kt < CC; kt += 32) {
        __syncthreads();
#pragma unroll
        for (int hl = 0; hl < 2; ++hl) {
            const unsigned short* Ap = hl ? alo : ahi;
            const unsigned short* Bp = hl ? blo : bhi;
#pragma unroll
            for (int i = 0; i < 4; ++i) {
                const int row = (i * 4 + w) * 16 + crow;
                const int sg  = asl ^ (row & 3);
                gload16(Ap + (size_t)(m0 + row) * 2048 + kt + sg * 8,
                        &As[hl][row][asl * 8]);
            }
#pragma unroll
            for (int i = 0; i < 2; ++i) {
                const int row = (i * 4 + w) * 16 + crow;
                const int sg  = asl ^ (row & 3);
                gload16(Bp + (size_t)(j0 + row) * 2048 + kt + sg * 8,
                        &Bs[hl][row][asl * 8]);
            }
        }
        __syncthreads();

        bf16x8 ah[8], al[8];
        const int sp = (g ^ (lr & 3)) * 8;
#pragma unroll
        for (int mi = 0; mi < 8; ++mi) {
            const int row = wr * 128 + mi * 16 + lr;
            ah[mi] = *(const bf16x8*)&As[0][row][sp];
            al[mi] = *(const bf16x8*)&As[1][row][sp];
        }
#pragma unroll
        for (int ni = 0; ni < 4; ++ni) {
            const int row = wc * 64 + ni * 16 + lr;
            const bf16x8 bh = *(const bf16x8*)&Bs[0][row][sp];
            const bf16x8 bl = *(const bf16x8*)&Bs[1][row][sp];
#pragma unroll
            for (int mi = 0; mi < 8; ++mi) {
                f32x4 t = acc[mi][ni];
                t = __builtin_amdgcn_mfma_f32_16x16x32_bf16(al[mi], bh, t, 0, 0, 0);
                t = __builtin_amdgcn_mfma_f32_16x16x32_bf16(ah[mi], bl, t, 0, 0, 0);
                t = __builtin_amdgcn_mfma_f32_16x16x32_bf16(ah[mi], bh, t, 0, 0, 0);
                acc[mi][ni] = t;
            }
        }
    }

    // C/D: col = lane&15, row = (lane>>4)*4 + reg  (validated r2/r3)
    const int p = j0 >> 11;
    const int h = (j0 & 2047) >> 7;
    float* outb = (p == 0) ? qb : ((p == 1) ? kb : vb);
#pragma unroll
    for (int mi = 0; mi < 8; ++mi) {
#pragma unroll
        for (int r = 0; r < 4; ++r) {
            const int gm = m0 + wr * 128 + mi * 16 + g * 4 + r;
            const int nb = gm >> 11;
            const int t  = gm & 2047;
            float* rowp = outb + ((size_t)(nb * HH + h) * TT + t) * DD;
#pragma unroll
            for (int ni = 0; ni < 4; ++ni)
                rowp[wc * 64 + ni * 16 + lr] = acc[mi][ni][r];
        }
    }
}

// ---------------------------------------------------------------------------
// bf16x3 MFMA out-projection: 128x128 tile, 4 waves 2x2, wave 64x64,
// gload_lds + swizzle staging.
// ---------------------------------------------------------------------------
__global__ __launch_bounds__(256, 3)
void mfma_oproj_kernel(const unsigned short* __restrict__ ahi,
                       const unsigned short* __restrict__ alo,
                       const unsigned short* __restrict__ bhi,
                       const unsigned short* __restrict__ blo,
                       float* __restrict__ outp)
{
    const int tid  = threadIdx.x;
    const int lane = tid & 63;
    const int w    = tid >> 6;
    const int wr   = w >> 1, wc = w & 1;
    const int lr   = lane & 15, g = lane >> 4;
    const int j0   = blockIdx.x * 128;
    const int m0   = blockIdx.y * 128;

    __shared__ __align__(16) unsigned short As[2][128][32];
    __shared__ __align__(16) unsigned short Bs[2][128][32];

    f32x4 acc[4][4];
#pragma unroll
    for (int mi = 0; mi < 4; ++mi)
#pragma unroll
        for (int ni = 0; ni < 4; ++ni) acc[mi][ni] = (f32x4){0.f, 0.f, 0.f, 0.f};

    const int crow = lane >> 2;
    const int asl  = lane & 3;

    for (int kt = 0; kt < CC; kt += 32) {
        __syncthreads();
#pragma unroll
        for (int hl = 0; hl < 2; ++hl) {
            const unsigned short* Ap = hl ? alo : ahi;
            const unsigned short* Bp = hl ? blo : bhi;
#pragma unroll
            for (int i = 0; i < 2; ++i) {
                const int row = (i * 4 + w) * 16 + crow;
                const int sg  = asl ^ (row & 3);
                gload16(Ap + (size_t)(m0 + row) * 2048 + kt + sg * 8,
                        &As[hl][row][asl * 8]);
                gload16(Bp + (size_t)(j0 + row) * 2048 + kt + sg * 8,
                        &Bs[hl][row][asl * 8]);
            }
        }
        __syncthreads();

        bf16x8 ah[4], al[4];
        const int sp = (g ^ (lr & 3)) * 8;
#pragma unroll
        for (int mi = 0; mi < 4; ++mi) {
            const int row = wr * 64 + mi * 16 + lr;
            ah[mi] = *(const bf16x8*)&As[0][row][sp];
            al[mi] = *(const bf16x8*)&As[1][row][sp];
        }
#pragma unroll
        for (int ni = 0; ni < 4; ++ni) {
            const int row = wc * 64 + ni * 16 + lr;
            const bf16x8 bh = *(const bf16x8*)&Bs[0][row][sp];
            const bf16x8 bl = *(const bf16x8*)&Bs[1][row][sp];
#pragma unroll
            for (int mi = 0; mi < 4; ++mi) {
                f32x4 t = acc[mi][ni];
                t = __builtin_amdgcn_mfma_f32_16x16x32_bf16(al[mi], bh, t, 0, 0, 0);
                t = __builtin_amdgcn_mfma_f32_16x16x32_bf16(ah[mi], bl, t, 0, 0, 0);
                t = __builtin_amdgcn_mfma_f32_16x16x32_bf16(ah[mi], bh, t, 0, 0, 0);
                acc[mi][ni] = t;
            }
        }
    }

#pragma unroll
    for (int mi = 0; mi < 4; ++mi) {
#pragma unroll
        for (int r = 0; r < 4; ++r) {
            const int gm = m0 + wr * 64 + mi * 16 + g * 4 + r;
            float* rowp = outp + (size_t)gm * 2048 + j0;
#pragma unroll
            for (int ni = 0; ni < 4; ++ni)
                rowp[wc * 64 + ni * 16 + lr] = acc[mi][ni][r];
        }
    }
}

// ---------------------------------------------------------------------------
// MFMA causal flash attention v2.
//   256 threads / 4 waves; QBLK=128 (wave owns 32 q-rows = 2 m-frags); KVB=64.
//   K pre-split hi/lo planes, V pre-transposed bf16 -> both staged with
//   global_load_lds (16B) + XOR swizzle at the bank floor.
//   QK^T bf16x3; PV bf16.  LPT: qt pairs sum to 15 across the 512 blocks.
// ---------------------------------------------------------------------------
#define KVB 64

__global__ __launch_bounds__(256, 2)
void attn_mfma_kernel(const float* __restrict__ qg,
                      const unsigned short* __restrict__ khi,
                      const unsigned short* __restrict__ klo,
                      const unsigned short* __restrict__ vtg,
                      unsigned short* __restrict__ yhi,
                      unsigned short* __restrict__ ylo)
{
    const int tid  = threadIdx.x;
    const int lane = tid & 63;
    const int w    = tid >> 6;          // 0..3
    const int lr   = lane & 15;
    const int g    = lane >> 4;
    const int bx   = blockIdx.x;
    const int g2   = bx >> 5;           // 0..15
    const int nh   = bx & 31;
    const int qt   = (g2 < 8) ? (15 - g2) : (g2 - 8);   // LPT pairs sum 15
    const int n    = nh >> 4;
    const int h    = nh & 15;
    const int qr0  = qt * 128;

    const float*          Q  = qg  + (size_t)nh * TT * DD;
    const unsigned short* Kh = khi + (size_t)nh * TT * DD;
    const unsigned short* Kl = klo + (size_t)nh * TT * DD;
    const unsigned short* Vt = vtg + (size_t)nh * DD * TT;

    __shared__ __align__(16) unsigned short Ks[2][64][128];  // 32 KB
    __shared__ __align__(16) unsigned short Vs[128][64];     // 16 KB
    __shared__ __align__(16) unsigned short Ps[4][32][72];   // 18 KB

    // Q fragments hi/lo: 2 m-frags x 4 kc, once per block
    bf16x8 qh[2][4], ql[2][4];
#pragma unroll
    for (int mf = 0; mf < 2; ++mf) {
        const int qr = qr0 + w * 32 + mf * 16 + lr;
#pragma unroll
        for (int kc = 0; kc < 4; ++kc) {
            const float* p = Q + (size_t)qr * DD + kc * 32 + g * 8;
            const float4 f0 = *(const float4*)p;
            const float4 f1 = *(const float4*)(p + 4);
            const float f[8] = {f0.x, f0.y, f0.z, f0.w, f1.x, f1.y, f1.z, f1.w};
            bf16x8 hv, lv;
#pragma unroll
            for (int j = 0; j < 8; ++j) {
                unsigned short hu, lu;
                split_bf16(f[j], hu, lu);
                hv[j] = (short)hu;
                lv[j] = (short)lu;
            }
            qh[mf][kc] = hv;
            ql[mf][kc] = lv;
        }
    }

    f32x4 o[2][8];
#pragma unroll
    for (int mf = 0; mf < 2; ++mf)
#pragma unroll
        for (int n2 = 0; n2 < 8; ++n2) o[mf][n2] = (f32x4){0.f, 0.f, 0.f, 0.f};
    float m2[2][4], ls[2][4];
#pragma unroll
    for (int mf = 0; mf < 2; ++mf)
#pragma unroll
        for (int r = 0; r < 4; ++r) { m2[mf][r] = -INFINITY; ls[mf][r] = 0.f; }

    const float c2 = 0.08838834764831845f * 1.44269504088896f;  // /sqrt(128)*log2e

    const int jmax = 2 * qt + 1;
    for (int jt = 0; jt <= jmax; ++jt) {
        const int s0 = jt * KVB;

        __syncthreads();
        // K: 32 chunks of 1KB (2 hl planes x 16); wave w takes chunks i*4+w
#pragma unroll
        for (int i = 0; i < 8; ++i) {
            const int chunk = i * 4 + w;
            const int hl = chunk >> 4;
            const int cl = chunk & 15;
            const int sl = cl * 4 + (lane >> 4);
            const int sp2 = lane & 15;
            const int sg  = sp2 ^ (sl & 7);
            gload16((hl ? Kl : Kh) + (size_t)(s0 + sl) * 128 + sg * 8,
                    &Ks[hl][sl][sp2 * 8]);
        }
        // V^T: 16 chunks
#pragma unroll
        for (int i = 0; i < 4; ++i) {
            const int chunk = i * 4 + w;
            const int dl  = chunk * 8 + (lane >> 3);
            const int sp2 = lane & 7;
            const int sg  = sp2 ^ (dl & 7);
            gload16(Vt + (size_t)dl * TT + s0 + sg * 8, &Vs[dl][sp2 * 8]);
        }
        __syncthreads();

        // ---- S = Q K^T (bf16x3) ----
        f32x4 sa[2][4];
#pragma unroll
        for (int mf = 0; mf < 2; ++mf)
#pragma unroll
            for (int nn = 0; nn < 4; ++nn) sa[mf][nn] = (f32x4){0.f, 0.f, 0.f, 0.f};
#pragma unroll
        for (int nn = 0; nn < 4; ++nn) {
#pragma unroll
            for (int kc = 0; kc < 4; ++kc) {
                const int sp2 = ((kc * 4 + g) ^ (lr & 7)) * 8;
                const bf16x8 kh = *(const bf16x8*)&Ks[0][nn * 16 + lr][sp2];
                const bf16x8 kl = *(const bf16x8*)&Ks[1][nn * 16 + lr][sp2];
#pragma unroll
                for (int mf = 0; mf < 2; ++mf) {
                    f32x4 t = sa[mf][nn];
                    t = __builtin_amdgcn_mfma_f32_16x16x32_bf16(ql[mf][kc], kh, t, 0, 0, 0);
                    t = __builtin_amdgcn_mfma_f32_16x16x32_bf16(qh[mf][kc], kl, t, 0, 0, 0);
                    t = __builtin_amdgcn_mfma_f32_16x16x32_bf16(qh[mf][kc], kh, t, 0, 0, 0);
                    sa[mf][nn] = t;
                }
            }
        }

        // ---- online softmax (exp2 domain) + P (bf16) ----
#pragma unroll
        for (int mf = 0; mf < 2; ++mf) {
            const int  qbase  = qr0 + w * 32 + mf * 16 + g * 4;
            const bool domask = (s0 + 63 > qr0 + w * 32 + mf * 16);
#pragma unroll
            for (int r = 0; r < 4; ++r) {
                float sv[4];
#pragma unroll
                for (int nn = 0; nn < 4; ++nn) {
                    float s = sa[mf][nn][r] * c2;
                    if (domask && (s0 + nn * 16 + lr > qbase + r)) s = -INFINITY;
                    sv[nn] = s;
                }
                float mr = fmaxf(fmaxf(sv[0], sv[1]), fmaxf(sv[2], sv[3]));
                mr = fmaxf(mr, __shfl_xor(mr, 1));
                mr = fmaxf(mr, __shfl_xor(mr, 2));
                mr = fmaxf(mr, __shfl_xor(mr, 4));
                mr = fmaxf(mr, __shfl_xor(mr, 8));
                const float mnew = fmaxf(m2[mf][r], mr);
                const float corr = exp2f(m2[mf][r] - mnew);   // 0 on first tile
                m2[mf][r] = mnew;
                float rs = 0.f;
#pragma unroll
                for (int nn = 0; nn < 4; ++nn) {
                    const float pv = exp2f(sv[nn] - mnew);
                    rs += pv;
                    Ps[w][mf * 16 + g * 4 + r][nn * 16 + lr] = bf16_rtn(pv);
                }
                rs += __shfl_xor(rs, 1);
                rs += __shfl_xor(rs, 2);
                rs += __shfl_xor(rs, 4);
                rs += __shfl_xor(rs, 8);
                ls[mf][r] = ls[mf][r] * corr + rs;
#pragma unroll
                for (int n2 = 0; n2 < 8; ++n2) o[mf][n2][r] *= corr;
            }
        }

        // ---- O += P V (own-wave P; within-wave LDS ordering) ----
#pragma unroll
        for (int kc2 = 0; kc2 < 2; ++kc2) {
            const bf16x8 pa0 = *(const bf16x8*)&Ps[w][lr][kc2 * 32 + g * 8];
            const bf16x8 pa1 = *(const bf16x8*)&Ps[w][16 + lr][kc2 * 32 + g * 8];
#pragma unroll
            for (int n2 = 0; n2 < 8; ++n2) {
                const int sp2 = ((kc2 * 4 + g) ^ (lr & 7)) * 8;
                const bf16x8 vb = *(const bf16x8*)&Vs[n2 * 16 + lr][sp2];
                o[0][n2] = __builtin_amdgcn_mfma_f32_16x16x32_bf16(pa0, vb, o[0][n2], 0, 0, 0);
                o[1][n2] = __builtin_amdgcn_mfma_f32_16x16x32_bf16(pa1, vb, o[1][n2], 0, 0, 0);
            }
        }
    }

    // ---- epilogue: y[m][h*128+d] hi/lo planes ----
#pragma unroll
    for (int mf = 0; mf < 2; ++mf) {
#pragma unroll
        for (int r = 0; r < 4; ++r) {
            const float inv = 1.f / ls[mf][r];
            const int gm = n * 2048 + qr0 + w * 32 + mf * 16 + g * 4 + r;
            const size_t base = (size_t)gm * 2048 + h * 128;
#pragma unroll
            for (int n2 = 0; n2 < 8; ++n2) {
                unsigned short hu, lu;
                split_bf16(o[mf][n2][r] * inv, hu, lu);
                yhi[base + n2 * 16 + lr] = hu;
                ylo[base + n2 * 16 + lr] = lu;
            }
        }
    }
}

// ---------------------------------------------------------------------------
// Fallback fp32 path (only if ws too small).
// ---------------------------------------------------------------------------
__global__ __launch_bounds__(256, 1)
void attn_kernel(const float* __restrict__ qg,
                 const float* __restrict__ kg,
                 const float* __restrict__ vg,
                 float* __restrict__ yf32)
{
    const int tid = threadIdx.x;
    const int tx  = tid & 15;
    const int ty  = tid >> 4;
    const int qt  = blockIdx.x;
    const int nh  = blockIdx.y;
    const int n   = nh >> 4;
    const int h   = nh & 15;

    const float* Q = qg + (size_t)nh * TT * DD;
    const float* K = kg + (size_t)nh * TT * DD;
    const float* V = vg + (size_t)nh * TT * DD;

    __shared__ float Qs[64][128];
    __shared__ float Ks2[64][128];
    __shared__ float Vs2[64][128];
    __shared__ float Ps2[64][68];

    const int qr0 = qt * 64;

#pragma unroll
    for (int it = 0; it < 8; ++it) {
        const int f4 = tid + it * 256;
        const int r  = f4 >> 5;
        const int c4 = f4 & 31;
        const float4 qv = *(const float4*)(Q + (size_t)(qr0 + r) * DD + c4 * 4);
        *(float4*)&Qs[r][(c4 ^ (r & 7)) << 2] = qv;
    }

    float acc[4][8];
#pragma unroll
    for (int i = 0; i < 4; ++i)
#pragma unroll
        for (int c = 0; c < 8; ++c) acc[i][c] = 0.f;

    float mrow[4], lrow[4];
#pragma unroll
    for (int i = 0; i < 4; ++i) { mrow[i] = -INFINITY; lrow[i] = 0.f; }

    const float sm_scale = 0.08838834764831845f;

    for (int jt = 0; jt <= qt; ++jt) {
        const int s0 = jt * 64;
        __syncthreads();
#pragma unroll
        for (int it = 0; it < 8; ++it) {
            const int f4 = tid + it * 256;
            const int r  = f4 >> 5;
            const int c4 = f4 & 31;
            const float4 kv = *(const float4*)(K + (size_t)(s0 + r) * DD + c4 * 4);
            *(float4*)&Ks2[r][(c4 ^ (r & 7)) << 2] = kv;
            const float4 vv = *(const float4*)(V + (size_t)(s0 + r) * DD + c4 * 4);
            *(float4*)&Vs2[r][c4 << 2] = vv;
        }
        __syncthreads();

        float S[4][4];
#pragma unroll
        for (int i = 0; i < 4; ++i)
#pragma unroll
            for (int j = 0; j < 4; ++j) S[i][j] = 0.f;

#pragma unroll 8
        for (int k4 = 0; k4 < 32; ++k4) {
            const int bsl = (k4 ^ (tx & 7)) << 2;
            const float4 b0 = *(const float4*)&Ks2[tx     ][bsl];
            const float4 b1 = *(const float4*)&Ks2[tx + 16][bsl];
            const float4 b2 = *(const float4*)&Ks2[tx + 32][bsl];
            const float4 b3 = *(const float4*)&Ks2[tx + 48][bsl];
#pragma unroll
            for (int i = 0; i < 4; ++i) {
                const int r = ty * 4 + i;
                const float4 a = *(const float4*)&Qs[r][(k4 ^ (r & 7)) << 2];
                S[i][0] = fmaf(a.w, b0.w, fmaf(a.z, b0.z, fmaf(a.y, b0.y, fmaf(a.x, b0.x, S[i][0]))));
                S[i][1] = fmaf(a.w, b1.w, fmaf(a.z, b1.z, fmaf(a.y, b1.y, fmaf(a.x, b1.x, S[i][1]))));
                S[i][2] = fmaf(a.w, b2.w, fmaf(a.z, b2.z, fmaf(a.y, b2.y, fmaf(a.x, b2.x, S[i][2]))));
                S[i][3] = fmaf(a.w, b3.w, fmaf(a.z, b3.z, fmaf(a.y, b3.y, fmaf(a.x, b3.x, S[i][3]))));
            }
        }

        const bool diag = (jt == qt);
#pragma unroll
        for (int i = 0; i < 4; ++i)
#pragma unroll
            for (int j = 0; j < 4; ++j) {
                float s = S[i][j] * sm_scale;
                if (diag && (tx + 16 * j > ty * 4 + i)) s = -INFINITY;
                S[i][j] = s;
            }

#pragma unroll
        for (int i = 0; i < 4; ++i) {
            float tm = fmaxf(fmaxf(S[i][0], S[i][1]), fmaxf(S[i][2], S[i][3]));
            tm = fmaxf(tm, __shfl_xor(tm, 1, 16));
            tm = fmaxf(tm, __shfl_xor(tm, 2, 16));
            tm = fmaxf(tm, __shfl_xor(tm, 4, 16));
            tm = fmaxf(tm, __shfl_xor(tm, 8, 16));
            const float mnew = fmaxf(mrow[i], tm);
            const float corr = expf(mrow[i] - mnew);
            mrow[i] = mnew;
            float rs = 0.f;
#pragma unroll
            for (int j = 0; j < 4; ++j) {
                const float pv = expf(S[i][j] - mnew);
                S[i][j] = pv;
                rs += pv;
            }
            rs += __shfl_xor(rs, 1, 16);
            rs += __shfl_xor(rs, 2, 16);
            rs += __shfl_xor(rs, 4, 16);
            rs += __shfl_xor(rs, 8, 16);
            lrow[i] = lrow[i] * corr + rs;
#pragma unroll
            for (int c = 0; c < 8; ++c) acc[i][c] *= corr;
            const int r = ty * 4 + i;
#pragma unroll
            for (int j = 0; j < 4; ++j) Ps2[r][tx + 16 * j] = S[i][j];
        }
        __syncthreads();

#pragma unroll 4
        for (int s4 = 0; s4 < 16; ++s4) {
            const float4 p0 = *(const float4*)&Ps2[ty * 4 + 0][s4 * 4];
            const float4 p1 = *(const float4*)&Ps2[ty * 4 + 1][s4 * 4];
            const float4 p2 = *(const float4*)&Ps2[ty * 4 + 2][s4 * 4];
            const float4 p3 = *(const float4*)&Ps2[ty * 4 + 3][s4 * 4];
            const float pa[4][4] = {{p0.x, p0.y, p0.z, p0.w},
                                    {p1.x, p1.y, p1.z, p1.w},
                                    {p2.x, p2.y, p2.z, p2.w},
                                    {p3.x, p3.y, p3.z, p3.w}};
#pragma unroll
            for (int ww = 0; ww < 4; ++ww) {
                const int s = s4 * 4 + ww;
                const float4 va = *(const float4*)&Vs2[s][tx * 4];
                const float4 vb = *(const float4*)&Vs2[s][64 + tx * 4];
#pragma unroll
                for (int i = 0; i < 4; ++i) {
                    const float pv = pa[i][ww];
                    acc[i][0] = fmaf(pv, va.x, acc[i][0]);
                    acc[i][1] = fmaf(pv, va.y, acc[i][1]);
                    acc[i][2] = fmaf(pv, va.z, acc[i][2]);
                    acc[i][3] = fmaf(pv, va.w, acc[i][3]);
                    acc[i][4] = fmaf(pv, vb.x, acc[i][4]);
                    acc[i][5] = fmaf(pv, vb.y, acc[i][5]);
                    acc[i][6] = fmaf(pv, vb.z, acc[i][6]);
                    acc[i][7] = fmaf(pv, vb.w, acc[i][7]);
                }
            }
        }
    }

#pragma unroll
    for (int i = 0; i < 4; ++i) {
        const float inv = 1.f / lrow[i];
        const int qr = qr0 + ty * 4 + i;
        float* rowp = yf32 + (size_t)(n * 2048 + qr) * 2048 + h * 128;
        const float4 o0 = make_float4(acc[i][0] * inv, acc[i][1] * inv, acc[i][2] * inv, acc[i][3] * inv);
        const float4 o1 = make_float4(acc[i][4] * inv, acc[i][5] * inv, acc[i][6] * inv, acc[i][7] * inv);
        *(float4*)(rowp + tx * 4)      = o0;
        *(float4*)(rowp + 64 + tx * 4) = o1;
    }
}

__global__ __launch_bounds__(256, 2)
void qkv_proj_kernel(const float* __restrict__ x,
                     const float* __restrict__ wq,
                     const float* __restrict__ wk,
                     const float* __restrict__ wv,
                     float* __restrict__ q_buf,
                     float* __restrict__ k_out,
                     float* __restrict__ v_out)
{
    const int tid = threadIdx.x;
    const int tx  = tid & 15;
    const int ty  = tid >> 4;
    const int j0  = blockIdx.x * 128;
    const int m0  = blockIdx.y * 128;

    const int    p   = j0 >> 11;
    const int    jw0 = j0 & 2047;
    const float* W    = (p == 0) ? wq    : ((p == 1) ? wk    : wv);
    float*       outb = (p == 0) ? q_buf : ((p == 1) ? k_out : v_out);

    __shared__ float At[16][132];
    __shared__ float Bt[16][132];

    float acc[8][8];
#pragma unroll
    for (int i = 0; i < 8; ++i)
#pragma unroll
        for (int j = 0; j < 8; ++j) acc[i][j] = 0.f;

    for (int kt = 0; kt < CC; kt += 16) {
        __syncthreads();
#pragma unroll
        for (int it = 0; it < 2; ++it) {
            const int f4  = tid + it * 256;
            const int row = f4 >> 2;
            const int kf4 = f4 & 3;
            const float4 a = *(const float4*)(x + (size_t)(m0 + row) * CC + kt + kf4 * 4);
            At[kf4 * 4 + 0][row] = a.x;
            At[kf4 * 4 + 1][row] = a.y;
            At[kf4 * 4 + 2][row] = a.z;
            At[kf4 * 4 + 3][row] = a.w;
            const float4 b = *(const float4*)(W + (size_t)(jw0 + row) * CC + kt + kf4 * 4);
            Bt[kf4 * 4 + 0][row] = b.x;
            Bt[kf4 * 4 + 1][row] = b.y;
            Bt[kf4 * 4 + 2][row] = b.z;
            Bt[kf4 * 4 + 3][row] = b.w;
        }
        __syncthreads();

#pragma unroll
        for (int k = 0; k < 16; ++k) {
            const float4 a0 = *(const float4*)&At[k][ty * 4];
            const float4 a1 = *(const float4*)&At[k][64 + ty * 4];
            const float4 b0 = *(const float4*)&Bt[k][tx * 4];
            const float4 b1 = *(const float4*)&Bt[k][64 + tx * 4];
            const float av[8] = {a0.x, a0.y, a0.z, a0.w, a1.x, a1.y, a1.z, a1.w};
            const float bv[8] = {b0.x, b0.y, b0.z, b0.w, b1.x, b1.y, b1.z, b1.w};
#pragma unroll
            for (int i = 0; i < 8; ++i)
#pragma unroll
                for (int j = 0; j < 8; ++j)
                    acc[i][j] = fmaf(av[i], bv[j], acc[i][j]);
        }
    }

    const int h = jw0 >> 7;
#pragma unroll
    for (int rh = 0; rh < 2; ++rh) {
#pragma unroll
        for (int i = 0; i < 4; ++i) {
            const int m = m0 + rh * 64 + ty * 4 + i;
            const int n = m >> 11;
            const int t = m & 2047;
            float* rowp = outb + ((size_t)(n * HH + h) * TT + t) * DD;
            const int ai = rh * 4 + i;
            const float4 o0 = make_float4(acc[ai][0], acc[ai][1], acc[ai][2], acc[ai][3]);
            const float4 o1 = make_float4(acc[ai][4], acc[ai][5], acc[ai][6], acc[ai][7]);
            *(float4*)(rowp + tx * 4)      = o0;
            *(float4*)(rowp + 64 + tx * 4) = o1;
        }
    }
}

__global__ __launch_bounds__(256, 2)
void out_proj_kernel(const float* __restrict__ y,
                     const float* __restrict__ wo,
                     float* __restrict__ out)
{
    const int tid = threadIdx.x;
    const int tx  = tid & 15;
    const int ty  = tid >> 4;
    const int c0  = blockIdx.x * 128;
    const int m0  = blockIdx.y * 128;

    __shared__ float At[16][132];
    __shared__ float Bs2[16][132];

    float acc[8][8];
#pragma unroll
    for (int i = 0; i < 8; ++i)
#pragma unroll
        for (int j = 0; j < 8; ++j) acc[i][j] = 0.f;

    for (int kt = 0; kt < 2048; kt += 16) {
        __syncthreads();
#pragma unroll
        for (int it = 0; it < 2; ++it) {
            const int f4 = tid + it * 256;
            {
                const int row = f4 >> 2;
                const int kf4 = f4 & 3;
                const float4 a = *(const float4*)(y + (size_t)(m0 + row) * 2048 + kt + kf4 * 4);
                At[kf4 * 4 + 0][row] = a.x;
                At[kf4 * 4 + 1][row] = a.y;
                At[kf4 * 4 + 2][row] = a.z;
                At[kf4 * 4 + 3][row] = a.w;
            }
            {
                const int row = f4 >> 5;
                const int cf4 = f4 & 31;
                const float4 b = *(const float4*)(wo + (size_t)(kt + row) * 2048 + c0 + cf4 * 4);
                *(float4*)&Bs2[row][cf4 * 4] = b;
            }
        }
        __syncthreads();

#pragma unroll
        for (int k = 0; k < 16; ++k) {
            const float4 a0 = *(const float4*)&At[k][ty * 4];
            const float4 a1 = *(const float4*)&At[k][64 + ty * 4];
            const float4 b0 = *(const float4*)&Bs2[k][tx * 4];
            const float4 b1 = *(const float4*)&Bs2[k][64 + tx * 4];
            const float av[8] = {a0.x, a0.y, a0.z, a0.w, a1.x, a1.y, a1.z, a1.w};
            const float bv[8] = {b0.x, b0.y, b0.z, b0.w, b1.x, b1.y, b1.z, b1.w};
#pragma unroll
            for (int i = 0; i < 8; ++i)
#pragma unroll
                for (int j = 0; j < 8; ++j)
                    acc[i][j] = fmaf(av[i], bv[j], acc[i][j]);
        }
    }

#pragma unroll
    for (int rh = 0; rh < 2; ++rh) {
#pragma unroll
        for (int i = 0; i < 4; ++i) {
            const int m  = m0 + rh * 64 + ty * 4 + i;
            const int ai = rh * 4 + i;
#pragma unroll
            for (int ch = 0; ch < 2; ++ch) {
                const float4 o = make_float4(acc[ai][ch * 4 + 0], acc[ai][ch * 4 + 1],
                                             acc[ai][ch * 4 + 2], acc[ai][ch * 4 + 3]);
                *(float4*)(out + (size_t)m * 2048 + c0 + ch * 64 + tx * 4) = o;
            }
        }
    }
}

// ---------------------------------------------------------------------------
extern "C" void kernel_launch(void* const* d_in, const int* in_sizes, int n_in,
                              void* d_out, int out_size, void* d_ws, size_t ws_size,
                              hipStream_t stream)
{
    const float* x  = (const float*)d_in[0];
    const float* wq = (const float*)d_in[1];
    const float* wk = (const float*)d_in[2];
    const float* wv = (const float*)d_in[3];
    const float* wo = (const float*)d_in[4];

    float* out   = (float*)d_out;
    float* k_out = out + ELEMS_OUT;
    float* v_out = k_out + ELEMS_KV;
    float* q_buf = out;                 // out slot unused until out-proj

    const size_t NEED = 134217728;      // 128 MiB of hi/lo planes
    if (ws_size >= NEED) {
        // ws (ushorts): x_hl | wqkv_hl | wot_hl | y_hl   == 128 MiB total.
        // Post-qkv, x planes are reused for k_hl and wqkv planes for v^T.
        unsigned short* xhi   = (unsigned short*)d_ws;
        unsigned short* xlo   = xhi + 8388608;
        unsigned short* whi   = xlo + 8388608;
        unsigned short* wlo   = whi + 12582912;
        unsigned short* wothi = wlo + 12582912;
        unsigned short* wotlo = wothi + 4194304;
        unsigned short* yhi   = wotlo + 4194304;
        unsigned short* ylo   = yhi + 8388608;

        unsigned short* khi = xhi;      // k planes reuse x region (dead post-qkv)
        unsigned short* klo = xlo;
        unsigned short* vt  = whi;      // v^T reuses w region (dead post-qkv)

        conv_hl<<<dim3(2048), dim3(256), 0, stream>>>(x, xhi, xlo, 2097152);
        conv_hl<<<dim3(1024), dim3(256), 0, stream>>>(wq, whi,           wlo,           1048576);
        conv_hl<<<dim3(1024), dim3(256), 0, stream>>>(wk, whi + 4194304, wlo + 4194304, 1048576);
        conv_hl<<<dim3(1024), dim3(256), 0, stream>>>(wv, whi + 8388608, wlo + 8388608, 1048576);
        tconv_kernel<<<dim3(64, 64), dim3(256), 0, stream>>>(wo, wothi, wotlo);

        mfma_qkv_kernel<<<dim3(48, 16), dim3(256), 0, stream>>>(xhi, xlo, whi, wlo,
                                                                q_buf, k_out, v_out);

        conv_hl<<<dim3(2048), dim3(256), 0, stream>>>(k_out, khi, klo, 2097152);
        vtrans_kernel<<<dim3(32, 32), dim3(256), 0, stream>>>(v_out, vt);

        attn_mfma_kernel<<<dim3(512), dim3(256), 0, stream>>>(q_buf, khi, klo, vt,
                                                              yhi, ylo);
        mfma_oproj_kernel<<<dim3(16, 32), dim3(256), 0, stream>>>(yhi, ylo, wothi, wotlo, out);
    } else {
        float* y_buf = (float*)d_ws;    // fp32 y, 33.6 MB
        qkv_proj_kernel<<<dim3(48, 32), dim3(256), 0, stream>>>(x, wq, wk, wv,
                                                                q_buf, k_out, v_out);
        attn_kernel<<<dim3(32, 32), dim3(256), 0, stream>>>(q_buf, k_out, v_out, y_buf);
        out_proj_kernel<<<dim3(16, 32), dim3(256), 0, stream>>>(y_buf, wo, out);
    }
}